// Round 1
// baseline (1009.560 us; speedup 1.0000x reference)
//
#include <hip/hip_runtime.h>
#include <math.h>

#define NTT 365
#define NSS 300
#define NHH 128
#define NROWS (NTT*NSS)   // 109500

__device__ __forceinline__ float sigf(float v) { return 1.0f / (1.0f + __expf(-v)); }

// ---------------- K1: per-site MLPs (fcW -> 896 raw, fcR -> 1024 raw) ----------------
__global__ __launch_bounds__(256) void k_site(
    const float* __restrict__ xc,
    const float* __restrict__ wW1, const float* __restrict__ bW1,
    const float* __restrict__ wW2, const float* __restrict__ bW2,
    const float* __restrict__ wR1, const float* __restrict__ bR1,
    const float* __restrict__ wR2, const float* __restrict__ bR2,
    float* __restrict__ wsite, float* __restrict__ rsite)
{
    __shared__ float xcb[10][32];
    __shared__ float hW[10][256];
    __shared__ float hR[10][256];
    int tid = threadIdx.x;
    int s0 = blockIdx.x * 10;
    for (int i = tid; i < 10 * 32; i += 256) xcb[i / 32][i % 32] = xc[s0 * 32 + i];
    __syncthreads();
    {
        int j = tid;
        float aW[10], aR[10];
#pragma unroll
        for (int r = 0; r < 10; ++r) { aW[r] = bW1[j]; aR[r] = bR1[j]; }
        for (int k = 0; k < 32; ++k) {
            float wv = wW1[j * 32 + k], rv = wR1[j * 32 + k];
#pragma unroll
            for (int r = 0; r < 10; ++r) { float xv = xcb[r][k]; aW[r] += xv * wv; aR[r] += xv * rv; }
        }
#pragma unroll
        for (int r = 0; r < 10; ++r) { hW[r][j] = tanhf(aW[r]); hR[r][j] = tanhf(aR[r]); }
    }
    __syncthreads();
    for (int o = tid; o < 896; o += 256) {
        float acc[10];
#pragma unroll
        for (int r = 0; r < 10; ++r) acc[r] = bW2[o];
        for (int k = 0; k < 256; ++k) {
            float wv = wW2[o * 256 + k];
#pragma unroll
            for (int r = 0; r < 10; ++r) acc[r] += hW[r][k] * wv;
        }
#pragma unroll
        for (int r = 0; r < 10; ++r) wsite[(s0 + r) * 896 + o] = acc[r];
    }
    for (int o = tid; o < 1024; o += 256) {
        float acc[10];
#pragma unroll
        for (int r = 0; r < 10; ++r) acc[r] = bR2[o];
        for (int k = 0; k < 256; ++k) {
            float wv = wR2[o * 256 + k];
#pragma unroll
            for (int r = 0; r < 10; ++r) acc[r] += hR[r][k] * wv;
        }
#pragma unroll
        for (int r = 0; r < 10; ++r) rsite[(s0 + r) * 1024 + o] = acc[r];
    }
}

// ---------------- K1b: softmax of ga over h per site ----------------
__global__ __launch_bounds__(128) void k_softmax_ga(const float* __restrict__ wsite,
                                                    float* __restrict__ ga)
{
    int s = blockIdx.x, tid = threadIdx.x;
    __shared__ float red[2];
    float v = wsite[s * 896 + 6 * 128 + tid];
    float m = v;
#pragma unroll
    for (int off = 32; off >= 1; off >>= 1) m = fmaxf(m, __shfl_xor(m, off));
    if ((tid & 63) == 0) red[tid >> 6] = m;
    __syncthreads();
    m = fmaxf(red[0], red[1]);
    __syncthreads();
    float e = __expf(v - m);
    float ssum = e;
#pragma unroll
    for (int off = 32; off >= 1; off >>= 1) ssum += __shfl_xor(ssum, off);
    if ((tid & 63) == 0) red[tid >> 6] = ssum;
    __syncthreads();
    ssum = red[0] + red[1];
    ga[s * 128 + tid] = e / ssum;
}

// ---------------- K2: fused fcT MLP over all (t,s) rows -> Pl, Ev, vm, Ps ----------------
__global__ __launch_bounds__(192) void k_fcT(
    const float* __restrict__ x, const float* __restrict__ xc,
    const float* __restrict__ w1, const float* __restrict__ b1,
    const float* __restrict__ w2, const float* __restrict__ b2,
    float* __restrict__ Ps, float* __restrict__ Pl,
    float* __restrict__ Ev, float* __restrict__ vmo)
{
    __shared__ float xb[64][38];
    __shared__ float vfb[64];
    __shared__ float hb[64][256];
    int tid = threadIdx.x;
    int row0 = blockIdx.x * 64;
    for (int idx = tid; idx < 64 * 38; idx += 192) {
        int r = idx / 38, c = idx - r * 38;
        int g = row0 + r;
        float val = 0.0f;
        if (g < NROWS) {
            if (c < 6) val = x[g * 6 + c];
            else { int s = g % NSS; val = xc[s * 32 + (c - 6)]; }
        }
        xb[r][c] = val;
    }
    __syncthreads();
    if (tid < 64) {
        int r = tid, g = row0 + r;
        float T1 = xb[r][2], T2 = xb[r][3];
        float den = T2 - T1;
        float dg = (den == 0.0f) ? 1.0f : den;
        float ratio = fminf(fmaxf((T1 + T2) / dg, -1.0f), 1.0f);
        float vf = acosf(ratio) * (1.0f / 3.1415f);
        vf = (T1 >= 0.0f) ? 0.0f : ((T2 <= 0.0f) ? 1.0f : vf);
        vfb[r] = vf;
        if (g < NROWS) Ps[g] = xb[r][0] * vf;
    }
    // phase 1: hidden layer
    for (int j = tid; j < 256; j += 192) {
        float w1r[38];
#pragma unroll
        for (int k = 0; k < 38; ++k) w1r[k] = w1[j * 38 + k];
        float bj = b1[j];
        for (int r = 0; r < 64; ++r) {
            float acc = bj;
#pragma unroll
            for (int k = 0; k < 38; ++k) acc += xb[r][k] * w1r[k];
            hb[r][j] = tanhf(acc);
        }
    }
    __syncthreads();
    // phase 2: 2 output columns per thread, 64 row accumulators
    int o0 = tid, o1 = tid + 192;
    float acc0[64], acc1[64];
    float bb0 = b2[o0], bb1 = b2[o1];
#pragma unroll
    for (int r = 0; r < 64; ++r) { acc0[r] = bb0; acc1[r] = bb1; }
    for (int kb = 0; kb < 256; kb += 8) {
        float wa[8], wb[8];
#pragma unroll
        for (int k2 = 0; k2 < 8; ++k2) { wa[k2] = w2[o0 * 256 + kb + k2]; wb[k2] = w2[o1 * 256 + kb + k2]; }
#pragma unroll
        for (int r = 0; r < 64; ++r) {
#pragma unroll
            for (int k2 = 0; k2 < 8; ++k2) {
                float hv = hb[r][kb + k2];
                acc0[r] += hv * wa[k2];
                acc1[r] += hv * wb[k2];
            }
        }
    }
    int cat0 = o0 >> 7, h0 = o0 & 127;   // cat0 in {0,1}
    int cat1 = o1 >> 7, h1 = o1 & 127;   // cat1 in {1,2}
#pragma unroll
    for (int r = 0; r < 64; ++r) {
        int g = row0 + r;
        if (g < NROWS) {
            float P = xb[r][0], E = xb[r][1], vf = vfb[r];
            float v0 = acc0[r];
            if (cat0 == 0) {
                float vi = fminf(fmaxf(v0 * (1.0f / 3.0f) + 0.5f, 0.0f), 1.0f);
                Pl[(size_t)g * 128 + h0] = P * (1.0f - vf) * vi;
            } else {
                Ev[(size_t)g * 128 + h0] = E * fmaxf(v0, 0.0f) * 2.0f;
            }
            float v1 = acc1[r];
            if (cat1 == 1) {
                Ev[(size_t)g * 128 + h1] = E * fmaxf(v1, 0.0f) * 2.0f;
            } else {
                vmo[(size_t)g * 128 + h1] = __expf(v1);
            }
        }
    }
}

// ---------------- K3: sequential scan + fused conv + reduce over 64 lanes ----------------
__global__ __launch_bounds__(64) void k_scan(
    const float* __restrict__ x, const float* __restrict__ xc,
    const float* __restrict__ wsite, const float* __restrict__ rsite,
    const float* __restrict__ gaw,
    const float* __restrict__ ctw, const float* __restrict__ ctb,
    const float* __restrict__ Ps, const float* __restrict__ Pl,
    const float* __restrict__ Ev, const float* __restrict__ vmv,
    float* __restrict__ pQ, float* __restrict__ pC)
{
    int lane = threadIdx.x;
    int b = blockIdx.x;
    int s = b >> 1, half = b & 1;
    int h = half * 64 + lane;
    const float* wrow = wsite + s * 896;
    float kp = sigf(wrow[0 * 128 + h]);
    float ks = sigf(wrow[1 * 128 + h]);
    float kg = sigf(wrow[2 * 128 + h]);
    float gp = sigf(wrow[3 * 128 + h]);
    float gL = __expf(wrow[4 * 128 + h]) * 2.0f;
    float qb = fmaxf(wrow[5 * 128 + h], 0.0f);
    float ga = gaw[s * 128 + h];
    float rt0 = fmaxf(rsite[s * 1024 + h * 8 + 0], 0.0f);
    float rt1 = fmaxf(rsite[s * 1024 + h * 8 + 1], 0.0f);
    float rt2 = fmaxf(rsite[s * 1024 + h * 8 + 2], 0.0f);
    float rt3 = fmaxf(rsite[s * 1024 + h * 8 + 3], 0.0f);
    float rt4 = fmaxf(rsite[s * 1024 + h * 8 + 4], 0.0f);
    float rt5 = fmaxf(rsite[s * 1024 + h * 8 + 5], 0.0f);
    float rt6 = fmaxf(rsite[s * 1024 + h * 8 + 6], 0.0f);
    float rt7 = fmaxf(rsite[s * 1024 + h * 8 + 7], 0.0f);
    const float L2E = 1.4426950408889634f;
    // fcCT: time-invariant precompute, per-step just 2 FMA + exp2 per gate
    float cpw0, cpw1, cpb, csw0, csw1, csb, cgw0, cgw1, cgb;
    {
        const float* wr = ctw + (0 * 128 + h) * 34;
        float base = ctb[0 * 128 + h];
        for (int k = 0; k < 32; ++k) base += wr[2 + k] * xc[s * 32 + k];
        cpw0 = wr[0] * L2E; cpw1 = wr[1] * L2E; cpb = base * L2E;
    }
    {
        const float* wr = ctw + (1 * 128 + h) * 34;
        float base = ctb[1 * 128 + h];
        for (int k = 0; k < 32; ++k) base += wr[2 + k] * xc[s * 32 + k];
        csw0 = wr[0] * L2E; csw1 = wr[1] * L2E; csb = base * L2E;
    }
    {
        const float* wr = ctw + (2 * 128 + h) * 34;
        float base = ctb[2 * 128 + h];
        for (int k = 0; k < 32; ++k) base += wr[2 + k] * xc[s * 32 + k];
        cgw0 = wr[0] * L2E; cgw1 = wr[1] * L2E; cgb = base * L2E;
    }
    float Sf = 0.0f, Ss = 0.0f, Sg = 0.0f;
    float q0 = 0, q1 = 0, q2 = 0, q3 = 0, q4 = 0, q5 = 0, q6 = 0, q7 = 0;
    float c0 = 0, c1 = 0, c2 = 0, c3 = 0, c4 = 0, c5 = 0, c6 = 0, c7 = 0;
    for (int t = 0; t < NTT; ++t) {
        int g = t * NSS + s;
        float psv = Ps[g];
        float T1 = x[g * 6 + 2], T2 = x[g * 6 + 3];
        float pl = Pl[(size_t)g * 128 + h];
        float ev = Ev[(size_t)g * 128 + h];
        float vm = vmv[(size_t)g * 128 + h];
        float t1v = Sf + psv;
        float qf = fminf(t1v, vm);
        Sf = fmaxf(t1v - vm, 0.0f);
        float H = fmaxf(Ss + pl + qf - ev, 0.0f);
        float qp = fmaxf(kp * (H - gL), 0.0f);
        float qs = ks * fminf(H, gL);
        Ss = H - qp - qs;
        float qso = qs * (1.0f - gp);
        float qsg = qs * gp;
        float tg = Sg + qsg;
        float qg = kg * tg + qb;
        Sg = tg - qg;
        float cp = exp2f(cpw0 * T1 + cpw1 * T2 + cpb);
        float cs = exp2f(csw0 * T1 + csw1 * T2 + csb);
        float cg = exp2f(cgw0 * T1 + cgw1 * T2 + cgb);
        float QS = qp + qso + qg;
        float CS = qp * cp * 0.1f + qso * cs + qg * cg;
        q0 += QS * rt0; q1 += QS * rt1; q2 += QS * rt2; q3 += QS * rt3;
        q4 += QS * rt4; q5 += QS * rt5; q6 += QS * rt6; q7 += QS * rt7;
        c0 += CS * rt0; c1 += CS * rt1; c2 += CS * rt2; c3 += CS * rt3;
        c4 += CS * rt4; c5 += CS * rt5; c6 += CS * rt6; c7 += CS * rt7;
        float qv = q0 * ga, cv = c0 * ga;
#pragma unroll
        for (int off = 32; off >= 1; off >>= 1) {
            qv += __shfl_xor(qv, off);
            cv += __shfl_xor(cv, off);
        }
        if (lane == 0) { pQ[g * 2 + half] = qv; pC[g * 2 + half] = cv; }
        q0 = q1; q1 = q2; q2 = q3; q3 = q4; q4 = q5; q5 = q6; q6 = q7; q7 = 0.0f;
        c0 = c1; c1 = c2; c2 = c3; c3 = c4; c4 = c5; c5 = c6; c6 = c7; c7 = 0.0f;
    }
}

// ---------------- K4: combine halves, divide ----------------
__global__ __launch_bounds__(256) void k_final(const float* __restrict__ pQ,
                                               const float* __restrict__ pC,
                                               float* __restrict__ out)
{
    int i = blockIdx.x * 256 + threadIdx.x;
    if (i < NROWS) {
        float q = pQ[i * 2] + pQ[i * 2 + 1];
        float c = pC[i * 2] + pC[i * 2 + 1];
        out[i] = q;
        out[NROWS + i] = c / q;
    }
}

extern "C" void kernel_launch(void* const* d_in, const int* in_sizes, int n_in,
                              void* d_out, int out_size, void* d_ws, size_t ws_size,
                              hipStream_t stream)
{
    const float* x      = (const float*)d_in[0];
    const float* xc     = (const float*)d_in[1];
    const float* fcR_w1 = (const float*)d_in[2];
    const float* fcR_b1 = (const float*)d_in[3];
    const float* fcR_w2 = (const float*)d_in[4];
    const float* fcR_b2 = (const float*)d_in[5];
    const float* fcW_w1 = (const float*)d_in[6];
    const float* fcW_b1 = (const float*)d_in[7];
    const float* fcW_w2 = (const float*)d_in[8];
    const float* fcW_b2 = (const float*)d_in[9];
    const float* fcT_w1 = (const float*)d_in[10];
    const float* fcT_b1 = (const float*)d_in[11];
    const float* fcT_w2 = (const float*)d_in[12];
    const float* fcT_b2 = (const float*)d_in[13];
    const float* fcCT_w = (const float*)d_in[14];
    const float* fcCT_b = (const float*)d_in[15];
    float* out = (float*)d_out;

    float* ws = (float*)d_ws;
    size_t o_w  = 0;                       // 300*896
    size_t o_r  = o_w + 300 * 896;         // 300*1024
    size_t o_ga = o_r + 300 * 1024;        // 300*128
    size_t o_Ps = o_ga + 300 * 128;        // 109500
    size_t o_Pl = o_Ps + NROWS;            // 109500*128
    size_t o_Ev = o_Pl + (size_t)NROWS * 128;
    size_t o_vm = o_Ev + (size_t)NROWS * 128;
    size_t o_pQ = o_vm + (size_t)NROWS * 128;
    size_t o_pC = o_pQ + (size_t)NROWS * 2;

    float* wsite = ws + o_w;
    float* rsite = ws + o_r;
    float* gaw   = ws + o_ga;
    float* Ps    = ws + o_Ps;
    float* Pl    = ws + o_Pl;
    float* Ev    = ws + o_Ev;
    float* vmw   = ws + o_vm;
    float* pQ    = ws + o_pQ;
    float* pC    = ws + o_pC;

    k_site<<<30, 256, 0, stream>>>(xc, fcW_w1, fcW_b1, fcW_w2, fcW_b2,
                                   fcR_w1, fcR_b1, fcR_w2, fcR_b2, wsite, rsite);
    k_softmax_ga<<<300, 128, 0, stream>>>(wsite, gaw);
    int nblk2 = (NROWS + 63) / 64;
    k_fcT<<<nblk2, 192, 0, stream>>>(x, xc, fcT_w1, fcT_b1, fcT_w2, fcT_b2,
                                     Ps, Pl, Ev, vmw);
    k_scan<<<600, 64, 0, stream>>>(x, xc, wsite, rsite, gaw, fcCT_w, fcCT_b,
                                   Ps, Pl, Ev, vmw, pQ, pC);
    k_final<<<(NROWS + 255) / 256, 256, 0, stream>>>(pQ, pC, out);
}

// Round 2
// 583.499 us; speedup vs baseline: 1.7302x; 1.7302x over previous
//
#include <hip/hip_runtime.h>
#include <math.h>

#define NTT 365
#define NSS 300
#define NROWS (NTT*NSS)   // 109500

using bf16x8 = __attribute__((ext_vector_type(8))) short;
using f32x4  = __attribute__((ext_vector_type(4))) float;

__device__ __forceinline__ float sigf(float v) { return 1.0f / (1.0f + __expf(-v)); }

__device__ __forceinline__ unsigned short f2bf(float f) {
    unsigned u = __builtin_bit_cast(unsigned, f);
    u += 0x7FFFu + ((u >> 16) & 1u);
    return (unsigned short)(u >> 16);
}

// ---------------- K0: convert fcT weights to bf16 (padded) ----------------
__global__ __launch_bounds__(256) void k_prep(const float* __restrict__ w1,
                                              const float* __restrict__ w2,
                                              unsigned short* __restrict__ w1bf,
                                              unsigned short* __restrict__ w2bf)
{
    int idx = blockIdx.x * 256 + threadIdx.x;
    if (idx < 256 * 64) {
        int k = idx & 63;
        int r = idx >> 6;
        w1bf[idx] = (k < 38) ? f2bf(w1[r * 38 + k]) : (unsigned short)0;
    }
    int idx2 = idx - 256 * 64;
    if (idx2 >= 0 && idx2 < 384 * 256) w2bf[idx2] = f2bf(w2[idx2]);
}

// ---------------- K1: per-site MLPs, output-sliced grid (30 x 8) ----------------
__global__ __launch_bounds__(256) void k_site(
    const float* __restrict__ xc,
    const float* __restrict__ wW1, const float* __restrict__ bW1,
    const float* __restrict__ wW2, const float* __restrict__ bW2,
    const float* __restrict__ wR1, const float* __restrict__ bR1,
    const float* __restrict__ wR2, const float* __restrict__ bR2,
    float* __restrict__ wsite, float* __restrict__ rsite)
{
    __shared__ float xcb[10][32];
    __shared__ float hW[10][256];
    __shared__ float hR[10][256];
    int tid = threadIdx.x;
    int s0 = blockIdx.x * 10;
    int os = blockIdx.y;              // 0..7 output slice
    for (int i = tid; i < 10 * 32; i += 256) xcb[i / 32][i % 32] = xc[s0 * 32 + i];
    __syncthreads();
    {
        int j = tid;
        float aW[10], aR[10];
#pragma unroll
        for (int r = 0; r < 10; ++r) { aW[r] = bW1[j]; aR[r] = bR1[j]; }
        for (int k = 0; k < 32; ++k) {
            float wv = wW1[j * 32 + k], rv = wR1[j * 32 + k];
#pragma unroll
            for (int r = 0; r < 10; ++r) { float xv = xcb[r][k]; aW[r] += xv * wv; aR[r] += xv * rv; }
        }
#pragma unroll
        for (int r = 0; r < 10; ++r) { hW[r][j] = tanhf(aW[r]); hR[r][j] = tanhf(aR[r]); }
    }
    __syncthreads();
    if (tid < 240) {
        int o_lin = os * 240 + tid;   // 0..1919
        float acc[10];
        if (o_lin < 896) {
            int o = o_lin;
#pragma unroll
            for (int r = 0; r < 10; ++r) acc[r] = bW2[o];
            for (int k = 0; k < 256; ++k) {
                float wv = wW2[o * 256 + k];
#pragma unroll
                for (int r = 0; r < 10; ++r) acc[r] += hW[r][k] * wv;
            }
#pragma unroll
            for (int r = 0; r < 10; ++r) wsite[(s0 + r) * 896 + o] = acc[r];
        } else {
            int o = o_lin - 896;      // 0..1023
#pragma unroll
            for (int r = 0; r < 10; ++r) acc[r] = bR2[o];
            for (int k = 0; k < 256; ++k) {
                float wv = wR2[o * 256 + k];
#pragma unroll
                for (int r = 0; r < 10; ++r) acc[r] += hR[r][k] * wv;
            }
#pragma unroll
            for (int r = 0; r < 10; ++r) rsite[(s0 + r) * 1024 + o] = acc[r];
        }
    }
}

// ---------------- K1b: softmax of ga over h per site ----------------
__global__ __launch_bounds__(128) void k_softmax_ga(const float* __restrict__ wsite,
                                                    float* __restrict__ ga)
{
    int s = blockIdx.x, tid = threadIdx.x;
    __shared__ float red[2];
    float v = wsite[s * 896 + 6 * 128 + tid];
    float m = v;
#pragma unroll
    for (int off = 32; off >= 1; off >>= 1) m = fmaxf(m, __shfl_xor(m, off));
    if ((tid & 63) == 0) red[tid >> 6] = m;
    __syncthreads();
    m = fmaxf(red[0], red[1]);
    __syncthreads();
    float e = __expf(v - m);
    float ssum = e;
#pragma unroll
    for (int off = 32; off >= 1; off >>= 1) ssum += __shfl_xor(ssum, off);
    if ((tid & 63) == 0) red[tid >> 6] = ssum;
    __syncthreads();
    ssum = red[0] + red[1];
    ga[s * 128 + tid] = e / ssum;
}

// ---------------- K2: fcT MLP via bf16 MFMA -> PT, Pl, Ev, vm ----------------
__global__ __launch_bounds__(512) void k_fcT(
    const float* __restrict__ x, const float* __restrict__ xc,
    const unsigned short* __restrict__ w1bf, const float* __restrict__ b1,
    const unsigned short* __restrict__ w2bf, const float* __restrict__ b2,
    float4* __restrict__ PT, float* __restrict__ Pl,
    float* __restrict__ Ev, float* __restrict__ vmo)
{
    __shared__ unsigned short A1[64][72];     // rows padded 64->72 shorts (bank spread)
    __shared__ unsigned short hb[64][264];    // 256 -> 264 pad
    __shared__ float xPE[64][2];
    __shared__ float vfb[64];
    int tid = threadIdx.x;
    int row0 = blockIdx.x * 64;

    for (int idx = tid; idx < 64 * 64; idx += 512) {
        int r = idx >> 6, c = idx & 63;
        int g = row0 + r;
        float val = 0.0f;
        if (g < NROWS) {
            if (c < 6) val = x[g * 6 + c];
            else if (c < 38) { int s = g % NSS; val = xc[s * 32 + (c - 6)]; }
        }
        A1[r][c] = f2bf(val);
    }
    if (tid < 64) {
        int r = tid, g = row0 + r;
        float P = 0, E = 0, T1 = 0, T2 = 0;
        if (g < NROWS) { P = x[g * 6]; E = x[g * 6 + 1]; T1 = x[g * 6 + 2]; T2 = x[g * 6 + 3]; }
        xPE[r][0] = P; xPE[r][1] = E;
        float den = T2 - T1;
        float dg = (den == 0.0f) ? 1.0f : den;
        float ratio = fminf(fmaxf((T1 + T2) / dg, -1.0f), 1.0f);
        float vf = acosf(ratio) * (1.0f / 3.1415f);
        vf = (T1 >= 0.0f) ? 0.0f : ((T2 <= 0.0f) ? 1.0f : vf);
        vfb[r] = vf;
        if (g < NROWS) PT[g] = make_float4(P * vf, T1, T2, vf);
    }
    __syncthreads();

    int lane = tid & 63, wv = tid >> 6;
    int r16 = lane & 15;
    int kg = (lane >> 4) * 8;     // k offset within 32-chunk
    int rq = (lane >> 4) * 4;     // row offset of C frag

    // ---- layer 1: [64 x 64(K pad)] @ [64 x 256] -> hidden ----
    {
        int mt = wv & 3, nb = (wv >> 2) * 8;
        f32x4 acc[8];
#pragma unroll
        for (int i = 0; i < 8; ++i) acc[i] = (f32x4){0.f, 0.f, 0.f, 0.f};
#pragma unroll
        for (int ks = 0; ks < 2; ++ks) {
            bf16x8 a = *(const bf16x8*)&A1[mt * 16 + r16][ks * 32 + kg];
#pragma unroll
            for (int i = 0; i < 8; ++i) {
                bf16x8 b = *(const bf16x8*)(w1bf + ((nb + i) * 16 + r16) * 64 + ks * 32 + kg);
                acc[i] = __builtin_amdgcn_mfma_f32_16x16x32_bf16(a, b, acc[i], 0, 0, 0);
            }
        }
#pragma unroll
        for (int i = 0; i < 8; ++i) {
            int col = (nb + i) * 16 + r16;
            float bias = b1[col];
#pragma unroll
            for (int j = 0; j < 4; ++j) {
                int row = mt * 16 + rq + j;
                hb[row][col] = f2bf(tanhf(acc[i][j] + bias));
            }
        }
    }
    __syncthreads();

    // ---- layer 2: [64 x 256] @ [256 x 384] ----
    {
        int rh = (wv & 1) * 32;        // row half
        int nq = (wv >> 1) * 96;       // col quarter
        f32x4 acc[2][6];
#pragma unroll
        for (int m = 0; m < 2; ++m)
#pragma unroll
            for (int i = 0; i < 6; ++i) acc[m][i] = (f32x4){0.f, 0.f, 0.f, 0.f};
#pragma unroll
        for (int ks = 0; ks < 8; ++ks) {
            bf16x8 a0 = *(const bf16x8*)&hb[rh + r16][ks * 32 + kg];
            bf16x8 a1 = *(const bf16x8*)&hb[rh + 16 + r16][ks * 32 + kg];
#pragma unroll
            for (int i = 0; i < 6; ++i) {
                bf16x8 b = *(const bf16x8*)(w2bf + (nq + i * 16 + r16) * 256 + ks * 32 + kg);
                acc[0][i] = __builtin_amdgcn_mfma_f32_16x16x32_bf16(a0, b, acc[0][i], 0, 0, 0);
                acc[1][i] = __builtin_amdgcn_mfma_f32_16x16x32_bf16(a1, b, acc[1][i], 0, 0, 0);
            }
        }
#pragma unroll
        for (int i = 0; i < 6; ++i) {
            int o = nq + i * 16 + r16;
            float bias = b2[o];
            int cat = o >> 7, h = o & 127;
#pragma unroll
            for (int m = 0; m < 2; ++m) {
#pragma unroll
                for (int j = 0; j < 4; ++j) {
                    int r = rh + m * 16 + rq + j;
                    int g = row0 + r;
                    if (g < NROWS) {
                        float v = acc[m][i][j] + bias;
                        if (cat == 0) {
                            float vi = fminf(fmaxf(v * (1.0f / 3.0f) + 0.5f, 0.0f), 1.0f);
                            Pl[(size_t)g * 128 + h] = xPE[r][0] * (1.0f - vfb[r]) * vi;
                        } else if (cat == 1) {
                            Ev[(size_t)g * 128 + h] = xPE[r][1] * fmaxf(v, 0.0f) * 2.0f;
                        } else {
                            vmo[(size_t)g * 128 + h] = __expf(v);
                        }
                    }
                }
            }
        }
    }
}

// ---------------- K3: scan + fused conv + reduce, 3-deep prefetch ----------------
__global__ __launch_bounds__(64) void k_scan(
    const float* __restrict__ xc,
    const float* __restrict__ wsite, const float* __restrict__ rsite,
    const float* __restrict__ gaw,
    const float* __restrict__ ctw, const float* __restrict__ ctb,
    const float4* __restrict__ PT,
    const float* __restrict__ Pl, const float* __restrict__ Ev,
    const float* __restrict__ vmv,
    float* __restrict__ pQ, float* __restrict__ pC)
{
    int lane = threadIdx.x;
    int b = blockIdx.x;
    int s = b >> 1, half = b & 1;
    int h = half * 64 + lane;
    const float* wrow = wsite + s * 896;
    float kp = sigf(wrow[0 * 128 + h]);
    float ks = sigf(wrow[1 * 128 + h]);
    float kg = sigf(wrow[2 * 128 + h]);
    float gp = sigf(wrow[3 * 128 + h]);
    float gL = __expf(wrow[4 * 128 + h]) * 2.0f;
    float qb = fmaxf(wrow[5 * 128 + h], 0.0f);
    float ga = gaw[s * 128 + h];
    float rt0 = fmaxf(rsite[s * 1024 + h * 8 + 0], 0.0f);
    float rt1 = fmaxf(rsite[s * 1024 + h * 8 + 1], 0.0f);
    float rt2 = fmaxf(rsite[s * 1024 + h * 8 + 2], 0.0f);
    float rt3 = fmaxf(rsite[s * 1024 + h * 8 + 3], 0.0f);
    float rt4 = fmaxf(rsite[s * 1024 + h * 8 + 4], 0.0f);
    float rt5 = fmaxf(rsite[s * 1024 + h * 8 + 5], 0.0f);
    float rt6 = fmaxf(rsite[s * 1024 + h * 8 + 6], 0.0f);
    float rt7 = fmaxf(rsite[s * 1024 + h * 8 + 7], 0.0f);
    const float L2E = 1.4426950408889634f;
    float cpw0, cpw1, cpb, csw0, csw1, csb, cgw0, cgw1, cgb;
    {
        const float* wr = ctw + (0 * 128 + h) * 34;
        float base = ctb[0 * 128 + h];
        for (int k = 0; k < 32; ++k) base += wr[2 + k] * xc[s * 32 + k];
        cpw0 = wr[0] * L2E; cpw1 = wr[1] * L2E; cpb = base * L2E;
    }
    {
        const float* wr = ctw + (1 * 128 + h) * 34;
        float base = ctb[1 * 128 + h];
        for (int k = 0; k < 32; ++k) base += wr[2 + k] * xc[s * 32 + k];
        csw0 = wr[0] * L2E; csw1 = wr[1] * L2E; csb = base * L2E;
    }
    {
        const float* wr = ctw + (2 * 128 + h) * 34;
        float base = ctb[2 * 128 + h];
        for (int k = 0; k < 32; ++k) base += wr[2 + k] * xc[s * 32 + k];
        cgw0 = wr[0] * L2E; cgw1 = wr[1] * L2E; cgb = base * L2E;
    }
    float Sf = 0.0f, Ss = 0.0f, Sg = 0.0f;
    float q0 = 0, q1 = 0, q2 = 0, q3 = 0, q4 = 0, q5 = 0, q6 = 0, q7 = 0;
    float c0 = 0, c1 = 0, c2 = 0, c3 = 0, c4 = 0, c5 = 0, c6 = 0, c7 = 0;

    float plb[4], evb[4], vmb[4];
    float4 ptb[4];
#pragma unroll
    for (int i = 0; i < 3; ++i) {
        int g = i * NSS + s;
        plb[i] = Pl[(size_t)g * 128 + h];
        evb[i] = Ev[(size_t)g * 128 + h];
        vmb[i] = vmv[(size_t)g * 128 + h];
        ptb[i] = PT[g];
    }
#pragma unroll 8
    for (int t = 0; t < NTT; ++t) {
        int sl = t & 3;
        int tp = t + 3;
        if (tp < NTT) {
            int gp = tp * NSS + s;
            int slp = tp & 3;
            plb[slp] = Pl[(size_t)gp * 128 + h];
            evb[slp] = Ev[(size_t)gp * 128 + h];
            vmb[slp] = vmv[(size_t)gp * 128 + h];
            ptb[slp] = PT[gp];
        }
        int g = t * NSS + s;
        float psv = ptb[sl].x, T1 = ptb[sl].y, T2 = ptb[sl].z;
        float pl = plb[sl], ev = evb[sl], vm = vmb[sl];
        float t1v = Sf + psv;
        float qf = fminf(t1v, vm);
        Sf = fmaxf(t1v - vm, 0.0f);
        float H = fmaxf(Ss + pl + qf - ev, 0.0f);
        float qp = fmaxf(kp * (H - gL), 0.0f);
        float qs = ks * fminf(H, gL);
        Ss = H - qp - qs;
        float qso = qs * (1.0f - gp);
        float qsg = qs * gp;
        float tg = Sg + qsg;
        float qg = kg * tg + qb;
        Sg = tg - qg;
        float cp = exp2f(cpw0 * T1 + cpw1 * T2 + cpb);
        float cs = exp2f(csw0 * T1 + csw1 * T2 + csb);
        float cg = exp2f(cgw0 * T1 + cgw1 * T2 + cgb);
        float QS = qp + qso + qg;
        float CS = qp * cp * 0.1f + qso * cs + qg * cg;
        q0 += QS * rt0; q1 += QS * rt1; q2 += QS * rt2; q3 += QS * rt3;
        q4 += QS * rt4; q5 += QS * rt5; q6 += QS * rt6; q7 += QS * rt7;
        c0 += CS * rt0; c1 += CS * rt1; c2 += CS * rt2; c3 += CS * rt3;
        c4 += CS * rt4; c5 += CS * rt5; c6 += CS * rt6; c7 += CS * rt7;
        float qv = q0 * ga, cv = c0 * ga;
#pragma unroll
        for (int off = 32; off >= 1; off >>= 1) {
            qv += __shfl_xor(qv, off);
            cv += __shfl_xor(cv, off);
        }
        if (lane == 0) { pQ[g * 2 + half] = qv; pC[g * 2 + half] = cv; }
        q0 = q1; q1 = q2; q2 = q3; q3 = q4; q4 = q5; q5 = q6; q6 = q7; q7 = 0.0f;
        c0 = c1; c1 = c2; c2 = c3; c3 = c4; c4 = c5; c5 = c6; c6 = c7; c7 = 0.0f;
    }
}

// ---------------- K4: combine halves, divide ----------------
__global__ __launch_bounds__(256) void k_final(const float* __restrict__ pQ,
                                               const float* __restrict__ pC,
                                               float* __restrict__ out)
{
    int i = blockIdx.x * 256 + threadIdx.x;
    if (i < NROWS) {
        float q = pQ[i * 2] + pQ[i * 2 + 1];
        float c = pC[i * 2] + pC[i * 2 + 1];
        out[i] = q;
        out[NROWS + i] = c / q;
    }
}

extern "C" void kernel_launch(void* const* d_in, const int* in_sizes, int n_in,
                              void* d_out, int out_size, void* d_ws, size_t ws_size,
                              hipStream_t stream)
{
    const float* x      = (const float*)d_in[0];
    const float* xc     = (const float*)d_in[1];
    const float* fcR_w1 = (const float*)d_in[2];
    const float* fcR_b1 = (const float*)d_in[3];
    const float* fcR_w2 = (const float*)d_in[4];
    const float* fcR_b2 = (const float*)d_in[5];
    const float* fcW_w1 = (const float*)d_in[6];
    const float* fcW_b1 = (const float*)d_in[7];
    const float* fcW_w2 = (const float*)d_in[8];
    const float* fcW_b2 = (const float*)d_in[9];
    const float* fcT_w1 = (const float*)d_in[10];
    const float* fcT_b1 = (const float*)d_in[11];
    const float* fcT_w2 = (const float*)d_in[12];
    const float* fcT_b2 = (const float*)d_in[13];
    const float* fcCT_w = (const float*)d_in[14];
    const float* fcCT_b = (const float*)d_in[15];
    float* out = (float*)d_out;

    float* ws = (float*)d_ws;
    size_t o_w    = 0;                                  // 300*896   = 268800
    size_t o_r    = o_w  + 300 * 896;                   // 300*1024  = 307200
    size_t o_ga   = o_r  + 300 * 1024;                  // 300*128   = 38400
    size_t o_PT   = o_ga + 300 * 128;                   // NROWS*4   = 438000
    size_t o_Pl   = o_PT + (size_t)NROWS * 4;           // NROWS*128
    size_t o_Ev   = o_Pl + (size_t)NROWS * 128;
    size_t o_vm   = o_Ev + (size_t)NROWS * 128;
    size_t o_pQ   = o_vm + (size_t)NROWS * 128;
    size_t o_pC   = o_pQ + (size_t)NROWS * 2;
    size_t o_w1bf = o_pC + (size_t)NROWS * 2;           // 16384 shorts = 8192 floats
    size_t o_w2bf = o_w1bf + 8192;                      // 98304 shorts = 49152 floats

    float* wsite = ws + o_w;
    float* rsite = ws + o_r;
    float* gaw   = ws + o_ga;
    float4* PT   = (float4*)(ws + o_PT);
    float* Pl    = ws + o_Pl;
    float* Ev    = ws + o_Ev;
    float* vmw   = ws + o_vm;
    float* pQ    = ws + o_pQ;
    float* pC    = ws + o_pC;
    unsigned short* w1bf = (unsigned short*)(ws + o_w1bf);
    unsigned short* w2bf = (unsigned short*)(ws + o_w2bf);

    k_prep<<<448, 256, 0, stream>>>(fcT_w1, fcT_w2, w1bf, w2bf);
    k_site<<<dim3(30, 8), 256, 0, stream>>>(xc, fcW_w1, fcW_b1, fcW_w2, fcW_b2,
                                            fcR_w1, fcR_b1, fcR_w2, fcR_b2, wsite, rsite);
    k_softmax_ga<<<300, 128, 0, stream>>>(wsite, gaw);
    int nblk2 = (NROWS + 63) / 64;   // 1711
    k_fcT<<<nblk2, 512, 0, stream>>>(x, xc, w1bf, fcT_b1, w2bf, fcT_b2,
                                     PT, Pl, Ev, vmw);
    k_scan<<<600, 64, 0, stream>>>(xc, wsite, rsite, gaw, fcCT_w, fcCT_b,
                                   PT, Pl, Ev, vmw, pQ, pC);
    k_final<<<(NROWS + 255) / 256, 256, 0, stream>>>(pQ, pC, out);
}

// Round 3
// 326.287 us; speedup vs baseline: 3.0941x; 1.7883x over previous
//
#include <hip/hip_runtime.h>
#include <math.h>

#define NTT 365
#define NSS 300
#define NROWS (NTT*NSS)   // 109500

using bf16x8 = __attribute__((ext_vector_type(8))) short;
using f32x4  = __attribute__((ext_vector_type(4))) float;

__device__ __forceinline__ float sigf(float v) { return 1.0f / (1.0f + __expf(-v)); }

__device__ __forceinline__ float tanhfast(float x) {
    float e = __expf(2.0f * x);
    return 1.0f - 2.0f * __builtin_amdgcn_rcpf(1.0f + e);
}

__device__ __forceinline__ unsigned short f2bf(float f) {
    unsigned u = __builtin_bit_cast(unsigned, f);
    u += 0x7FFFu + ((u >> 16) & 1u);
    return (unsigned short)(u >> 16);
}

// ---------------- K0: convert fcT weights to bf16 (padded) ----------------
__global__ __launch_bounds__(256) void k_prep(const float* __restrict__ w1,
                                              const float* __restrict__ w2,
                                              unsigned short* __restrict__ w1bf,
                                              unsigned short* __restrict__ w2bf)
{
    int idx = blockIdx.x * 256 + threadIdx.x;
    if (idx < 256 * 64) {
        int k = idx & 63;
        int r = idx >> 6;
        w1bf[idx] = (k < 38) ? f2bf(w1[r * 38 + k]) : (unsigned short)0;
    }
    int idx2 = idx - 256 * 64;
    if (idx2 >= 0 && idx2 < 384 * 256) w2bf[idx2] = f2bf(w2[idx2]);
}

// ---------------- K1: per-site MLPs, output-sliced grid (30 x 8) ----------------
__global__ __launch_bounds__(256) void k_site(
    const float* __restrict__ xc,
    const float* __restrict__ wW1, const float* __restrict__ bW1,
    const float* __restrict__ wW2, const float* __restrict__ bW2,
    const float* __restrict__ wR1, const float* __restrict__ bR1,
    const float* __restrict__ wR2, const float* __restrict__ bR2,
    float* __restrict__ wsite, float* __restrict__ rsite)
{
    __shared__ float xcb[10][32];
    __shared__ float hW[10][256];
    __shared__ float hR[10][256];
    int tid = threadIdx.x;
    int s0 = blockIdx.x * 10;
    int os = blockIdx.y;              // 0..7 output slice
    for (int i = tid; i < 10 * 32; i += 256) xcb[i / 32][i % 32] = xc[s0 * 32 + i];
    __syncthreads();
    {
        int j = tid;
        float aW[10], aR[10];
#pragma unroll
        for (int r = 0; r < 10; ++r) { aW[r] = bW1[j]; aR[r] = bR1[j]; }
        for (int k = 0; k < 32; ++k) {
            float wv = wW1[j * 32 + k], rv = wR1[j * 32 + k];
#pragma unroll
            for (int r = 0; r < 10; ++r) { float xv = xcb[r][k]; aW[r] += xv * wv; aR[r] += xv * rv; }
        }
#pragma unroll
        for (int r = 0; r < 10; ++r) { hW[r][j] = tanhfast(aW[r]); hR[r][j] = tanhfast(aR[r]); }
    }
    __syncthreads();
    if (tid < 240) {
        int o_lin = os * 240 + tid;   // 0..1919
        float acc[10];
        if (o_lin < 896) {
            int o = o_lin;
#pragma unroll
            for (int r = 0; r < 10; ++r) acc[r] = bW2[o];
            for (int k = 0; k < 256; ++k) {
                float wv = wW2[o * 256 + k];
#pragma unroll
                for (int r = 0; r < 10; ++r) acc[r] += hW[r][k] * wv;
            }
#pragma unroll
            for (int r = 0; r < 10; ++r) wsite[(s0 + r) * 896 + o] = acc[r];
        } else {
            int o = o_lin - 896;      // 0..1023
#pragma unroll
            for (int r = 0; r < 10; ++r) acc[r] = bR2[o];
            for (int k = 0; k < 256; ++k) {
                float wv = wR2[o * 256 + k];
#pragma unroll
                for (int r = 0; r < 10; ++r) acc[r] += hR[r][k] * wv;
            }
#pragma unroll
            for (int r = 0; r < 10; ++r) rsite[(s0 + r) * 1024 + o] = acc[r];
        }
    }
}

// ---------------- K1b: softmax of ga over h per site ----------------
__global__ __launch_bounds__(128) void k_softmax_ga(const float* __restrict__ wsite,
                                                    float* __restrict__ ga)
{
    int s = blockIdx.x, tid = threadIdx.x;
    __shared__ float red[2];
    float v = wsite[s * 896 + 6 * 128 + tid];
    float m = v;
#pragma unroll
    for (int off = 32; off >= 1; off >>= 1) m = fmaxf(m, __shfl_xor(m, off));
    if ((tid & 63) == 0) red[tid >> 6] = m;
    __syncthreads();
    m = fmaxf(red[0], red[1]);
    __syncthreads();
    float e = __expf(v - m);
    float ssum = e;
#pragma unroll
    for (int off = 32; off >= 1; off >>= 1) ssum += __shfl_xor(ssum, off);
    if ((tid & 63) == 0) red[tid >> 6] = ssum;
    __syncthreads();
    ssum = red[0] + red[1];
    ga[s * 128 + tid] = e / ssum;
}

// ---------------- K2: fcT MLP via bf16 MFMA -> PT, NET(=Pl-Ev), VM ----------------
// Wave w owns column tiles {w, w+8, w+16} so the SAME lane holds vi/ve/vm for one h.
__global__ __launch_bounds__(512) void k_fcT(
    const float* __restrict__ x, const float* __restrict__ xc,
    const unsigned short* __restrict__ w1bf, const float* __restrict__ b1,
    const unsigned short* __restrict__ w2bf, const float* __restrict__ b2,
    float4* __restrict__ PT, float* __restrict__ NET, float* __restrict__ VM)
{
    __shared__ unsigned short A1[64][72];
    __shared__ unsigned short hb[64][264];
    __shared__ float2 pfE[64];           // {P*(1-vf), 2*E}
    int tid = threadIdx.x;
    int row0 = blockIdx.x * 64;

    for (int idx = tid; idx < 64 * 64; idx += 512) {
        int r = idx >> 6, c = idx & 63;
        int g = row0 + r;
        float val = 0.0f;
        if (g < NROWS) {
            if (c < 6) val = x[g * 6 + c];
            else if (c < 38) { int s = g % NSS; val = xc[s * 32 + (c - 6)]; }
        }
        A1[r][c] = f2bf(val);
    }
    if (tid < 64) {
        int r = tid, g = row0 + r;
        float P = 0, E = 0, T1 = 0, T2 = 0;
        if (g < NROWS) { P = x[g * 6]; E = x[g * 6 + 1]; T1 = x[g * 6 + 2]; T2 = x[g * 6 + 3]; }
        float den = T2 - T1;
        float dg = (den == 0.0f) ? 1.0f : den;
        float ratio = fminf(fmaxf((T1 + T2) / dg, -1.0f), 1.0f);
        float vf = acosf(ratio) * (1.0f / 3.1415f);
        vf = (T1 >= 0.0f) ? 0.0f : ((T2 <= 0.0f) ? 1.0f : vf);
        pfE[r] = make_float2(P * (1.0f - vf), 2.0f * E);
        if (g < NROWS) PT[g] = make_float4(P * vf, T1, T2, vf);
    }
    __syncthreads();

    int lane = tid & 63, wv = tid >> 6;
    int r16 = lane & 15;
    int kg = (lane >> 4) * 8;     // k offset within 32-chunk
    int rq = (lane >> 4) * 4;     // row offset of C frag

    // ---- layer 1: [64 x 64(Kpad)] @ [256 x 64]^T -> hidden (bf16) ----
    {
        int mt = wv & 3, nb = (wv >> 2) * 8;
        f32x4 acc[8];
#pragma unroll
        for (int i = 0; i < 8; ++i) acc[i] = (f32x4){0.f, 0.f, 0.f, 0.f};
#pragma unroll
        for (int ks = 0; ks < 2; ++ks) {
            bf16x8 a = *(const bf16x8*)&A1[mt * 16 + r16][ks * 32 + kg];
#pragma unroll
            for (int i = 0; i < 8; ++i) {
                bf16x8 b = *(const bf16x8*)(w1bf + ((nb + i) * 16 + r16) * 64 + ks * 32 + kg);
                acc[i] = __builtin_amdgcn_mfma_f32_16x16x32_bf16(a, b, acc[i], 0, 0, 0);
            }
        }
#pragma unroll
        for (int i = 0; i < 8; ++i) {
            int col = (nb + i) * 16 + r16;
            float bias = b1[col];
#pragma unroll
            for (int j = 0; j < 4; ++j) {
                int row = mt * 16 + rq + j;
                hb[row][col] = f2bf(tanhfast(acc[i][j] + bias));
            }
        }
    }
    __syncthreads();

    // ---- layer 2: [64 x 256] @ [384 x 256]^T, wave w -> col tiles {w, w+8, w+16} ----
    {
        int cb0 = wv * 16, cb1 = 128 + wv * 16, cb2 = 256 + wv * 16;
        f32x4 acc[4][3];
#pragma unroll
        for (int m = 0; m < 4; ++m)
#pragma unroll
            for (int c = 0; c < 3; ++c) acc[m][c] = (f32x4){0.f, 0.f, 0.f, 0.f};
#pragma unroll
        for (int ks = 0; ks < 8; ++ks) {
            bf16x8 b0 = *(const bf16x8*)(w2bf + (cb0 + r16) * 256 + ks * 32 + kg);
            bf16x8 b1v = *(const bf16x8*)(w2bf + (cb1 + r16) * 256 + ks * 32 + kg);
            bf16x8 b2v = *(const bf16x8*)(w2bf + (cb2 + r16) * 256 + ks * 32 + kg);
#pragma unroll
            for (int m = 0; m < 4; ++m) {
                bf16x8 a = *(const bf16x8*)&hb[m * 16 + r16][ks * 32 + kg];
                acc[m][0] = __builtin_amdgcn_mfma_f32_16x16x32_bf16(a, b0, acc[m][0], 0, 0, 0);
                acc[m][1] = __builtin_amdgcn_mfma_f32_16x16x32_bf16(a, b1v, acc[m][1], 0, 0, 0);
                acc[m][2] = __builtin_amdgcn_mfma_f32_16x16x32_bf16(a, b2v, acc[m][2], 0, 0, 0);
            }
        }
        int hcol = cb0 + r16;     // h in [0,128)
        float bias0 = b2[cb0 + r16], bias1 = b2[cb1 + r16], bias2 = b2[cb2 + r16];
#pragma unroll
        for (int m = 0; m < 4; ++m) {
            float2 pf[4];
#pragma unroll
            for (int j = 0; j < 4; ++j) pf[j] = pfE[m * 16 + rq + j];
#pragma unroll
            for (int j = 0; j < 4; ++j) {
                int r = m * 16 + rq + j;
                int g = row0 + r;
                if (g < NROWS) {
                    float vi = fminf(fmaxf((acc[m][0][j] + bias0) * (1.0f / 3.0f) + 0.5f, 0.0f), 1.0f);
                    float pl = pf[j].x * vi;
                    float ev = pf[j].y * fmaxf(acc[m][1][j] + bias1, 0.0f);
                    NET[(size_t)g * 128 + hcol] = pl - ev;
                    VM[(size_t)g * 128 + hcol] = __expf(acc[m][2][j] + bias2);
                }
            }
        }
    }
}

// ---------------- K3: scan + fused conv, deep prefetch + batched LDS reduce ----------------
__global__ __launch_bounds__(64) void k_scan(
    const float* __restrict__ xc,
    const float* __restrict__ wsite, const float* __restrict__ rsite,
    const float* __restrict__ gaw,
    const float* __restrict__ ctw, const float* __restrict__ ctb,
    const float4* __restrict__ PT,
    const float* __restrict__ NET, const float* __restrict__ VM,
    float* __restrict__ pQ, float* __restrict__ pC)
{
    __shared__ __align__(16) float red[16][68];   // rows 0..7: q, 8..15: c
    int lane = threadIdx.x;
    int b = blockIdx.x;
    int s = b >> 1, half = b & 1;
    int h = half * 64 + lane;
    const float* wrow = wsite + s * 896;
    float kp = sigf(wrow[0 * 128 + h]);
    float ks = sigf(wrow[1 * 128 + h]);
    float kg = sigf(wrow[2 * 128 + h]);
    float gp = sigf(wrow[3 * 128 + h]);
    float gpc = 1.0f - gp;
    float gL = __expf(wrow[4 * 128 + h]) * 2.0f;
    float qb = fmaxf(wrow[5 * 128 + h], 0.0f);
    float ga = gaw[s * 128 + h];
    float rt0 = fmaxf(rsite[s * 1024 + h * 8 + 0], 0.0f);
    float rt1 = fmaxf(rsite[s * 1024 + h * 8 + 1], 0.0f);
    float rt2 = fmaxf(rsite[s * 1024 + h * 8 + 2], 0.0f);
    float rt3 = fmaxf(rsite[s * 1024 + h * 8 + 3], 0.0f);
    float rt4 = fmaxf(rsite[s * 1024 + h * 8 + 4], 0.0f);
    float rt5 = fmaxf(rsite[s * 1024 + h * 8 + 5], 0.0f);
    float rt6 = fmaxf(rsite[s * 1024 + h * 8 + 6], 0.0f);
    float rt7 = fmaxf(rsite[s * 1024 + h * 8 + 7], 0.0f);
    const float L2E = 1.4426950408889634f;
    const float LG01 = -3.3219280948873623f;      // log2(0.1): folds the /10 into cp
    float cpw0, cpw1, cpb, csw0, csw1, csb, cgw0, cgw1, cgb;
    {
        const float* wr = ctw + (0 * 128 + h) * 34;
        float base = ctb[0 * 128 + h];
        for (int k = 0; k < 32; ++k) base += wr[2 + k] * xc[s * 32 + k];
        cpw0 = wr[0] * L2E; cpw1 = wr[1] * L2E; cpb = base * L2E + LG01;
    }
    {
        const float* wr = ctw + (1 * 128 + h) * 34;
        float base = ctb[1 * 128 + h];
        for (int k = 0; k < 32; ++k) base += wr[2 + k] * xc[s * 32 + k];
        csw0 = wr[0] * L2E; csw1 = wr[1] * L2E; csb = base * L2E;
    }
    {
        const float* wr = ctw + (2 * 128 + h) * 34;
        float base = ctb[2 * 128 + h];
        for (int k = 0; k < 32; ++k) base += wr[2 + k] * xc[s * 32 + k];
        cgw0 = wr[0] * L2E; cgw1 = wr[1] * L2E; cgb = base * L2E;
    }
    float Sf = 0.0f, Ss = 0.0f, Sg = 0.0f;
    float q0 = 0, q1 = 0, q2 = 0, q3 = 0, q4 = 0, q5 = 0, q6 = 0, q7 = 0;
    float c0 = 0, c1 = 0, c2 = 0, c3 = 0, c4 = 0, c5 = 0, c6 = 0, c7 = 0;

    // depth-8 register rings
    float netb[8], vmb[8], ptx[8], pty[8], ptz[8];
#pragma unroll
    for (int i = 0; i < 8; ++i) {
        int g = i * NSS + s;
        netb[i] = NET[(size_t)g * 128 + h];
        vmb[i]  = VM[(size_t)g * 128 + h];
        float4 p = PT[g];
        ptx[i] = p.x; pty[i] = p.y; ptz[i] = p.z;
    }

    for (int tb = 0; tb < 368; tb += 8) {
#pragma unroll
        for (int u = 0; u < 8; ++u) {
            int t = tb + u;
            float net = netb[u], vm = vmb[u];
            float psv = ptx[u], T1 = pty[u], T2 = ptz[u];
            int tp = t + 8;
            if (tp < NTT) {
                size_t gp = (size_t)(tp * NSS + s);
                netb[u] = NET[gp * 128 + h];
                vmb[u]  = VM[gp * 128 + h];
                float4 p = PT[gp];
                ptx[u] = p.x; pty[u] = p.y; ptz[u] = p.z;
            }
            float t1v = Sf + psv;
            float qf = fminf(t1v, vm);
            Sf = fmaxf(t1v - vm, 0.0f);
            float H = fmaxf(Ss + qf + net, 0.0f);
            float qp = fmaxf(kp * (H - gL), 0.0f);
            float qs = ks * fminf(H, gL);
            Ss = H - qp - qs;
            float qso = qs * gpc;
            float qsg = qs * gp;
            float tg = Sg + qsg;
            float qg = kg * tg + qb;
            Sg = tg - qg;
            float cp = exp2f(cpw0 * T1 + cpw1 * T2 + cpb);
            float cs = exp2f(csw0 * T1 + csw1 * T2 + csb);
            float cg = exp2f(cgw0 * T1 + cgw1 * T2 + cgb);
            float QS = qp + qso + qg;
            float CS = qp * cp + qso * cs + qg * cg;
            q0 += QS * rt0; q1 += QS * rt1; q2 += QS * rt2; q3 += QS * rt3;
            q4 += QS * rt4; q5 += QS * rt5; q6 += QS * rt6; q7 += QS * rt7;
            c0 += CS * rt0; c1 += CS * rt1; c2 += CS * rt2; c3 += CS * rt3;
            c4 += CS * rt4; c5 += CS * rt5; c6 += CS * rt6; c7 += CS * rt7;
            red[u][lane] = q0 * ga;
            red[8 + u][lane] = c0 * ga;
            q0 = q1; q1 = q2; q2 = q3; q3 = q4; q4 = q5; q5 = q6; q6 = q7; q7 = 0.0f;
            c0 = c1; c1 = c2; c2 = c3; c3 = c4; c4 = c5; c5 = c6; c6 = c7; c7 = 0.0f;
        }
        // reduce 16 rows x 64 lanes: 4 lanes per row, 16 elems each, then 2-level shuffle
        {
            int v = lane >> 2, sub = lane & 3;
            const float4* rp = (const float4*)&red[v][0];
            float4 a0 = rp[sub * 4 + 0];
            float4 a1 = rp[sub * 4 + 1];
            float4 a2 = rp[sub * 4 + 2];
            float4 a3 = rp[sub * 4 + 3];
            float sA = (a0.x + a0.y) + (a0.z + a0.w);
            float sB = (a1.x + a1.y) + (a1.z + a1.w);
            float sC = (a2.x + a2.y) + (a2.z + a2.w);
            float sD = (a3.x + a3.y) + (a3.z + a3.w);
            float sm = (sA + sB) + (sC + sD);
            sm += __shfl_xor(sm, 1);
            sm += __shfl_xor(sm, 2);
            int u2 = v & 7;
            int t = tb + u2;
            if (sub == 0 && t < NTT) {
                float* bp = (v < 8) ? pQ : pC;
                bp[((size_t)t * NSS + s) * 2 + half] = sm;
            }
        }
    }
}

// ---------------- K4: combine halves, divide ----------------
__global__ __launch_bounds__(256) void k_final(const float* __restrict__ pQ,
                                               const float* __restrict__ pC,
                                               float* __restrict__ out)
{
    int i = blockIdx.x * 256 + threadIdx.x;
    if (i < NROWS) {
        float q = pQ[i * 2] + pQ[i * 2 + 1];
        float c = pC[i * 2] + pC[i * 2 + 1];
        out[i] = q;
        out[NROWS + i] = c / q;
    }
}

extern "C" void kernel_launch(void* const* d_in, const int* in_sizes, int n_in,
                              void* d_out, int out_size, void* d_ws, size_t ws_size,
                              hipStream_t stream)
{
    const float* x      = (const float*)d_in[0];
    const float* xc     = (const float*)d_in[1];
    const float* fcR_w1 = (const float*)d_in[2];
    const float* fcR_b1 = (const float*)d_in[3];
    const float* fcR_w2 = (const float*)d_in[4];
    const float* fcR_b2 = (const float*)d_in[5];
    const float* fcW_w1 = (const float*)d_in[6];
    const float* fcW_b1 = (const float*)d_in[7];
    const float* fcW_w2 = (const float*)d_in[8];
    const float* fcW_b2 = (const float*)d_in[9];
    const float* fcT_w1 = (const float*)d_in[10];
    const float* fcT_b1 = (const float*)d_in[11];
    const float* fcT_w2 = (const float*)d_in[12];
    const float* fcT_b2 = (const float*)d_in[13];
    const float* fcCT_w = (const float*)d_in[14];
    const float* fcCT_b = (const float*)d_in[15];
    float* out = (float*)d_out;

    float* ws = (float*)d_ws;
    size_t o_w    = 0;                                  // 300*896
    size_t o_r    = o_w  + 300 * 896;
    size_t o_ga   = o_r  + 300 * 1024;
    size_t o_PT   = o_ga + 300 * 128;                   // NROWS*4 (float4, 16B aligned)
    size_t o_NET  = o_PT + (size_t)NROWS * 4;
    size_t o_VM   = o_NET + (size_t)NROWS * 128;
    size_t o_pQ   = o_VM  + (size_t)NROWS * 128;
    size_t o_pC   = o_pQ  + (size_t)NROWS * 2;
    size_t o_w1bf = o_pC  + (size_t)NROWS * 2;
    size_t o_w2bf = o_w1bf + 8192;

    float* wsite = ws + o_w;
    float* rsite = ws + o_r;
    float* gaw   = ws + o_ga;
    float4* PT   = (float4*)(ws + o_PT);
    float* NET   = ws + o_NET;
    float* VM    = ws + o_VM;
    float* pQ    = ws + o_pQ;
    float* pC    = ws + o_pC;
    unsigned short* w1bf = (unsigned short*)(ws + o_w1bf);
    unsigned short* w2bf = (unsigned short*)(ws + o_w2bf);

    k_prep<<<448, 256, 0, stream>>>(fcT_w1, fcT_w2, w1bf, w2bf);
    k_site<<<dim3(30, 8), 256, 0, stream>>>(xc, fcW_w1, fcW_b1, fcW_w2, fcW_b2,
                                            fcR_w1, fcR_b1, fcR_w2, fcR_b2, wsite, rsite);
    k_softmax_ga<<<300, 128, 0, stream>>>(wsite, gaw);
    int nblk2 = (NROWS + 63) / 64;   // 1711
    k_fcT<<<nblk2, 512, 0, stream>>>(x, xc, w1bf, fcT_b1, w2bf, fcT_b2,
                                     PT, NET, VM);
    k_scan<<<600, 64, 0, stream>>>(xc, wsite, rsite, gaw, fcCT_w, fcCT_b,
                                   PT, NET, VM, pQ, pC);
    k_final<<<(NROWS + 255) / 256, 256, 0, stream>>>(pQ, pC, out);
}

// Round 4
// 201.809 us; speedup vs baseline: 5.0026x; 1.6168x over previous
//
#include <hip/hip_runtime.h>
#include <math.h>

#define NTT 365
#define NSS 300
#define NROWS (NTT*NSS)   // 109500
#define TPAD 384          // padded time steps for branchless prefetch

using bf16x8 = __attribute__((ext_vector_type(8))) short;
using f32x4  = __attribute__((ext_vector_type(4))) float;

__device__ __forceinline__ float sigf(float v) { return 1.0f / (1.0f + __expf(-v)); }

__device__ __forceinline__ float tanhfast(float x) {
    float e = __expf(2.0f * x);
    return 1.0f - 2.0f * __builtin_amdgcn_rcpf(1.0f + e);
}

__device__ __forceinline__ unsigned short f2bf(float f) {
    unsigned u = __builtin_bit_cast(unsigned, f);
    u += 0x7FFFu + ((u >> 16) & 1u);
    return (unsigned short)(u >> 16);
}

// ---------------- K0: convert fcT weights to bf16 (padded) ----------------
__global__ __launch_bounds__(256) void k_prep(const float* __restrict__ w1,
                                              const float* __restrict__ w2,
                                              unsigned short* __restrict__ w1bf,
                                              unsigned short* __restrict__ w2bf)
{
    int idx = blockIdx.x * 256 + threadIdx.x;
    if (idx < 256 * 64) {
        int k = idx & 63;
        int r = idx >> 6;
        w1bf[idx] = (k < 38) ? f2bf(w1[r * 38 + k]) : (unsigned short)0;
    }
    int idx2 = idx - 256 * 64;
    if (idx2 >= 0 && idx2 < 384 * 256) w2bf[idx2] = f2bf(w2[idx2]);
}

// ---------------- K1: per-site MLPs, output-sliced grid (30 x 8) ----------------
__global__ __launch_bounds__(256) void k_site(
    const float* __restrict__ xc,
    const float* __restrict__ wW1, const float* __restrict__ bW1,
    const float* __restrict__ wW2, const float* __restrict__ bW2,
    const float* __restrict__ wR1, const float* __restrict__ bR1,
    const float* __restrict__ wR2, const float* __restrict__ bR2,
    float* __restrict__ wsite, float* __restrict__ rsite)
{
    __shared__ float xcb[10][32];
    __shared__ float hW[10][256];
    __shared__ float hR[10][256];
    int tid = threadIdx.x;
    int s0 = blockIdx.x * 10;
    int os = blockIdx.y;              // 0..7 output slice
    for (int i = tid; i < 10 * 32; i += 256) xcb[i / 32][i % 32] = xc[s0 * 32 + i];
    __syncthreads();
    {
        int j = tid;
        float aW[10], aR[10];
#pragma unroll
        for (int r = 0; r < 10; ++r) { aW[r] = bW1[j]; aR[r] = bR1[j]; }
        for (int k = 0; k < 32; ++k) {
            float wv = wW1[j * 32 + k], rv = wR1[j * 32 + k];
#pragma unroll
            for (int r = 0; r < 10; ++r) { float xv = xcb[r][k]; aW[r] += xv * wv; aR[r] += xv * rv; }
        }
#pragma unroll
        for (int r = 0; r < 10; ++r) { hW[r][j] = tanhfast(aW[r]); hR[r][j] = tanhfast(aR[r]); }
    }
    __syncthreads();
    if (tid < 240) {
        int o_lin = os * 240 + tid;   // 0..1919
        float acc[10];
        if (o_lin < 896) {
            int o = o_lin;
#pragma unroll
            for (int r = 0; r < 10; ++r) acc[r] = bW2[o];
            for (int k = 0; k < 256; ++k) {
                float wv = wW2[o * 256 + k];
#pragma unroll
                for (int r = 0; r < 10; ++r) acc[r] += hW[r][k] * wv;
            }
#pragma unroll
            for (int r = 0; r < 10; ++r) wsite[(s0 + r) * 896 + o] = acc[r];
        } else {
            int o = o_lin - 896;      // 0..1023
#pragma unroll
            for (int r = 0; r < 10; ++r) acc[r] = bR2[o];
            for (int k = 0; k < 256; ++k) {
                float wv = wR2[o * 256 + k];
#pragma unroll
                for (int r = 0; r < 10; ++r) acc[r] += hR[r][k] * wv;
            }
#pragma unroll
            for (int r = 0; r < 10; ++r) rsite[(s0 + r) * 1024 + o] = acc[r];
        }
    }
}

// ---------------- K1b: softmax of ga over h per site ----------------
__global__ __launch_bounds__(128) void k_softmax_ga(const float* __restrict__ wsite,
                                                    float* __restrict__ ga)
{
    int s = blockIdx.x, tid = threadIdx.x;
    __shared__ float red[2];
    float v = wsite[s * 896 + 6 * 128 + tid];
    float m = v;
#pragma unroll
    for (int off = 32; off >= 1; off >>= 1) m = fmaxf(m, __shfl_xor(m, off));
    if ((tid & 63) == 0) red[tid >> 6] = m;
    __syncthreads();
    m = fmaxf(red[0], red[1]);
    __syncthreads();
    float e = __expf(v - m);
    float ssum = e;
#pragma unroll
    for (int off = 32; off >= 1; off >>= 1) ssum += __shfl_xor(ssum, off);
    if ((tid & 63) == 0) red[tid >> 6] = ssum;
    __syncthreads();
    ssum = red[0] + red[1];
    ga[s * 128 + tid] = e / ssum;
}

// ---------------- K2: fcT MLP via bf16 MFMA -> PT, NV{net, vm} ----------------
__global__ __launch_bounds__(512) void k_fcT(
    const float* __restrict__ x, const float* __restrict__ xc,
    const unsigned short* __restrict__ w1bf, const float* __restrict__ b1,
    const unsigned short* __restrict__ w2bf, const float* __restrict__ b2,
    float4* __restrict__ PT, float2* __restrict__ NV)
{
    __shared__ unsigned short A1[64][72];
    __shared__ unsigned short hb[64][264];
    __shared__ float2 pfE[64];           // {P*(1-vf), 2*E}
    int tid = threadIdx.x;
    int row0 = blockIdx.x * 64;

    for (int idx = tid; idx < 64 * 64; idx += 512) {
        int r = idx >> 6, c = idx & 63;
        int g = row0 + r;
        float val = 0.0f;
        if (g < NROWS) {
            if (c < 6) val = x[g * 6 + c];
            else if (c < 38) { int s = g % NSS; val = xc[s * 32 + (c - 6)]; }
        }
        A1[r][c] = f2bf(val);
    }
    if (tid < 64) {
        int r = tid, g = row0 + r;
        float P = 0, E = 0, T1 = 0, T2 = 0;
        if (g < NROWS) { P = x[g * 6]; E = x[g * 6 + 1]; T1 = x[g * 6 + 2]; T2 = x[g * 6 + 3]; }
        float den = T2 - T1;
        float dg = (den == 0.0f) ? 1.0f : den;
        float ratio = fminf(fmaxf((T1 + T2) / dg, -1.0f), 1.0f);
        float vf = acosf(ratio) * (1.0f / 3.1415f);
        vf = (T1 >= 0.0f) ? 0.0f : ((T2 <= 0.0f) ? 1.0f : vf);
        pfE[r] = make_float2(P * (1.0f - vf), 2.0f * E);
        if (g < NROWS) PT[g] = make_float4(P * vf, T1, T2, vf);
    }
    __syncthreads();

    int lane = tid & 63, wv = tid >> 6;
    int r16 = lane & 15;
    int kg = (lane >> 4) * 8;     // k offset within 32-chunk
    int rq = (lane >> 4) * 4;     // row offset of C frag

    // ---- layer 1: [64 x 64(Kpad)] @ [256 x 64]^T -> hidden (bf16) ----
    {
        int mt = wv & 3, nb = (wv >> 2) * 8;
        f32x4 acc[8];
#pragma unroll
        for (int i = 0; i < 8; ++i) acc[i] = (f32x4){0.f, 0.f, 0.f, 0.f};
#pragma unroll
        for (int ks = 0; ks < 2; ++ks) {
            bf16x8 a = *(const bf16x8*)&A1[mt * 16 + r16][ks * 32 + kg];
#pragma unroll
            for (int i = 0; i < 8; ++i) {
                bf16x8 b = *(const bf16x8*)(w1bf + ((nb + i) * 16 + r16) * 64 + ks * 32 + kg);
                acc[i] = __builtin_amdgcn_mfma_f32_16x16x32_bf16(a, b, acc[i], 0, 0, 0);
            }
        }
#pragma unroll
        for (int i = 0; i < 8; ++i) {
            int col = (nb + i) * 16 + r16;
            float bias = b1[col];
#pragma unroll
            for (int j = 0; j < 4; ++j) {
                int row = mt * 16 + rq + j;
                hb[row][col] = f2bf(tanhfast(acc[i][j] + bias));
            }
        }
    }
    __syncthreads();

    // ---- layer 2: [64 x 256] @ [384 x 256]^T, wave w -> col tiles {w, w+8, w+16} ----
    {
        int cb0 = wv * 16, cb1 = 128 + wv * 16, cb2 = 256 + wv * 16;
        f32x4 acc[4][3];
#pragma unroll
        for (int m = 0; m < 4; ++m)
#pragma unroll
            for (int c = 0; c < 3; ++c) acc[m][c] = (f32x4){0.f, 0.f, 0.f, 0.f};
#pragma unroll
        for (int ks = 0; ks < 8; ++ks) {
            bf16x8 b0 = *(const bf16x8*)(w2bf + (cb0 + r16) * 256 + ks * 32 + kg);
            bf16x8 b1v = *(const bf16x8*)(w2bf + (cb1 + r16) * 256 + ks * 32 + kg);
            bf16x8 b2v = *(const bf16x8*)(w2bf + (cb2 + r16) * 256 + ks * 32 + kg);
#pragma unroll
            for (int m = 0; m < 4; ++m) {
                bf16x8 a = *(const bf16x8*)&hb[m * 16 + r16][ks * 32 + kg];
                acc[m][0] = __builtin_amdgcn_mfma_f32_16x16x32_bf16(a, b0, acc[m][0], 0, 0, 0);
                acc[m][1] = __builtin_amdgcn_mfma_f32_16x16x32_bf16(a, b1v, acc[m][1], 0, 0, 0);
                acc[m][2] = __builtin_amdgcn_mfma_f32_16x16x32_bf16(a, b2v, acc[m][2], 0, 0, 0);
            }
        }
        int hcol = cb0 + r16;     // h in [0,128)
        float bias0 = b2[cb0 + r16], bias1 = b2[cb1 + r16], bias2 = b2[cb2 + r16];
#pragma unroll
        for (int m = 0; m < 4; ++m) {
            float2 pf[4];
#pragma unroll
            for (int j = 0; j < 4; ++j) pf[j] = pfE[m * 16 + rq + j];
#pragma unroll
            for (int j = 0; j < 4; ++j) {
                int r = m * 16 + rq + j;
                int g = row0 + r;
                if (g < NROWS) {
                    float vi = fminf(fmaxf((acc[m][0][j] + bias0) * (1.0f / 3.0f) + 0.5f, 0.0f), 1.0f);
                    float pl = pf[j].x * vi;
                    float ev = pf[j].y * fmaxf(acc[m][1][j] + bias1, 0.0f);
                    float vmv = __expf(acc[m][2][j] + bias2);
                    NV[(size_t)g * 128 + hcol] = make_float2(pl - ev, vmv);
                }
            }
        }
    }
}

// ---------------- K3: scan + fused conv; branchless 16-deep prefetch ----------------
__global__ __launch_bounds__(64) void k_scan(
    const float* __restrict__ xc,
    const float* __restrict__ wsite, const float* __restrict__ rsite,
    const float* __restrict__ gaw,
    const float* __restrict__ ctw, const float* __restrict__ ctb,
    const float4* __restrict__ PTg, const float2* __restrict__ NV,
    float* __restrict__ pQ, float* __restrict__ pC)
{
    __shared__ float4 ptlds[TPAD];                 // 6144 B
    __shared__ __align__(16) float red[16][68];    // 4352 B; rows 0..7 q, 8..15 c
    int lane = threadIdx.x;
    int b = blockIdx.x;
    int s = b >> 1, half = b & 1;
    int h = half * 64 + lane;

    // one-time PT stage (single wave per block: no barrier needed)
    for (int t = lane; t < TPAD; t += 64) ptlds[t] = PTg[(size_t)t * NSS + s];

    const float* wrow = wsite + s * 896;
    float kp = sigf(wrow[0 * 128 + h]);
    float ks = sigf(wrow[1 * 128 + h]);
    float kg = sigf(wrow[2 * 128 + h]);
    float gp = sigf(wrow[3 * 128 + h]);
    float gpc = 1.0f - gp;
    float gL = __expf(wrow[4 * 128 + h]) * 2.0f;
    float kpgl = kp * gL;
    float qb = fmaxf(wrow[5 * 128 + h], 0.0f);
    float ga = gaw[s * 128 + h];
    float rt0 = fmaxf(rsite[s * 1024 + h * 8 + 0], 0.0f) * ga;
    float rt1 = fmaxf(rsite[s * 1024 + h * 8 + 1], 0.0f) * ga;
    float rt2 = fmaxf(rsite[s * 1024 + h * 8 + 2], 0.0f) * ga;
    float rt3 = fmaxf(rsite[s * 1024 + h * 8 + 3], 0.0f) * ga;
    float rt4 = fmaxf(rsite[s * 1024 + h * 8 + 4], 0.0f) * ga;
    float rt5 = fmaxf(rsite[s * 1024 + h * 8 + 5], 0.0f) * ga;
    float rt6 = fmaxf(rsite[s * 1024 + h * 8 + 6], 0.0f) * ga;
    float rt7 = fmaxf(rsite[s * 1024 + h * 8 + 7], 0.0f) * ga;
    const float L2E = 1.4426950408889634f;
    const float LG01 = -3.3219280948873623f;      // log2(0.1): folds the /10 into cp
    float cpw0, cpw1, cpb, csw0, csw1, csb, cgw0, cgw1, cgb;
    {
        const float* wr = ctw + (0 * 128 + h) * 34;
        float base = ctb[0 * 128 + h];
        for (int k = 0; k < 32; ++k) base += wr[2 + k] * xc[s * 32 + k];
        cpw0 = wr[0] * L2E; cpw1 = wr[1] * L2E; cpb = base * L2E + LG01;
    }
    {
        const float* wr = ctw + (1 * 128 + h) * 34;
        float base = ctb[1 * 128 + h];
        for (int k = 0; k < 32; ++k) base += wr[2 + k] * xc[s * 32 + k];
        csw0 = wr[0] * L2E; csw1 = wr[1] * L2E; csb = base * L2E;
    }
    {
        const float* wr = ctw + (2 * 128 + h) * 34;
        float base = ctb[2 * 128 + h];
        for (int k = 0; k < 32; ++k) base += wr[2 + k] * xc[s * 32 + k];
        cgw0 = wr[0] * L2E; cgw1 = wr[1] * L2E; cgb = base * L2E;
    }
    float Sf = 0.0f, Ss = 0.0f, Sg = 0.0f;
    float q0 = 0, q1 = 0, q2 = 0, q3 = 0, q4 = 0, q5 = 0, q6 = 0, q7 = 0;
    float c0 = 0, c1 = 0, c2 = 0, c3 = 0, c4 = 0, c5 = 0, c6 = 0, c7 = 0;

    // 16-deep NV register ring (branchless: arrays padded to TPAD steps)
    const float2* nvbase = NV + (size_t)s * 128 + h;
    float2 nv[16];
#pragma unroll
    for (int i = 0; i < 16; ++i) nv[i] = nvbase[(size_t)i * NSS * 128];

    // 2-deep PT pipeline from LDS
    float4 ptc = ptlds[0];
    float4 ptn = ptlds[1];

    auto reduce8 = [&](int base) {
        int v = lane >> 2, sub = lane & 3;
        const float4* rp = (const float4*)&red[v][0];
        float4 a0 = rp[sub * 4 + 0];
        float4 a1 = rp[sub * 4 + 1];
        float4 a2 = rp[sub * 4 + 2];
        float4 a3 = rp[sub * 4 + 3];
        float sA = (a0.x + a0.y) + (a0.z + a0.w);
        float sB = (a1.x + a1.y) + (a1.z + a1.w);
        float sC = (a2.x + a2.y) + (a2.z + a2.w);
        float sD = (a3.x + a3.y) + (a3.z + a3.w);
        float sm = (sA + sB) + (sC + sD);
        sm += __shfl_xor(sm, 1);
        sm += __shfl_xor(sm, 2);
        int t = base + (v & 7);
        if (sub == 0 && t < NTT) {
            float* bp = (v < 8) ? pQ : pC;
            bp[((size_t)t * NSS + s) * 2 + half] = sm;
        }
    };

    for (int tb = 0; tb < 368; tb += 16) {
#pragma unroll
        for (int u = 0; u < 16; ++u) {
            int t = tb + u;
            float net = nv[u].x, vm = nv[u].y;
            // branchless prefetch, 16 ahead (padded arrays)
            nv[u] = nvbase[(size_t)(t + 16) * NSS * 128];
            float psv = ptc.x, T1 = ptc.y, T2 = ptc.z;
            ptc = ptn;
            ptn = ptlds[t + 2];
            float t1v = Sf + psv;
            float qf = fminf(t1v, vm);
            Sf = fmaxf(t1v - vm, 0.0f);
            float H = fmaxf(Ss + qf + net, 0.0f);
            float qp = fmaxf(kp * H - kpgl, 0.0f);
            float qs = ks * fminf(H, gL);
            Ss = H - qp - qs;
            float qso = qs * gpc;
            float qsg = qs * gp;
            float tg = Sg + qsg;
            float qg = kg * tg + qb;
            Sg = tg - qg;
            float cp = exp2f(cpw0 * T1 + cpw1 * T2 + cpb);
            float cs = exp2f(csw0 * T1 + csw1 * T2 + csb);
            float cg = exp2f(cgw0 * T1 + cgw1 * T2 + cgb);
            float QS = qp + qso + qg;
            float CS = qp * cp + qso * cs + qg * cg;
            q0 += QS * rt0; q1 += QS * rt1; q2 += QS * rt2; q3 += QS * rt3;
            q4 += QS * rt4; q5 += QS * rt5; q6 += QS * rt6; q7 += QS * rt7;
            c0 += CS * rt0; c1 += CS * rt1; c2 += CS * rt2; c3 += CS * rt3;
            c4 += CS * rt4; c5 += CS * rt5; c6 += CS * rt6; c7 += CS * rt7;
            red[u & 7][lane] = q0;
            red[8 + (u & 7)][lane] = c0;
            q0 = q1; q1 = q2; q2 = q3; q3 = q4; q4 = q5; q5 = q6; q6 = q7; q7 = 0.0f;
            c0 = c1; c1 = c2; c2 = c3; c3 = c4; c4 = c5; c5 = c6; c6 = c7; c7 = 0.0f;
            if (u == 7) reduce8(tb);
            if (u == 15) reduce8(tb + 8);
        }
    }
}

// ---------------- K4: combine halves, divide ----------------
__global__ __launch_bounds__(256) void k_final(const float* __restrict__ pQ,
                                               const float* __restrict__ pC,
                                               float* __restrict__ out)
{
    int i = blockIdx.x * 256 + threadIdx.x;
    if (i < NROWS) {
        float q = pQ[i * 2] + pQ[i * 2 + 1];
        float c = pC[i * 2] + pC[i * 2 + 1];
        out[i] = q;
        out[NROWS + i] = c / q;
    }
}

extern "C" void kernel_launch(void* const* d_in, const int* in_sizes, int n_in,
                              void* d_out, int out_size, void* d_ws, size_t ws_size,
                              hipStream_t stream)
{
    const float* x      = (const float*)d_in[0];
    const float* xc     = (const float*)d_in[1];
    const float* fcR_w1 = (const float*)d_in[2];
    const float* fcR_b1 = (const float*)d_in[3];
    const float* fcR_w2 = (const float*)d_in[4];
    const float* fcR_b2 = (const float*)d_in[5];
    const float* fcW_w1 = (const float*)d_in[6];
    const float* fcW_b1 = (const float*)d_in[7];
    const float* fcW_w2 = (const float*)d_in[8];
    const float* fcW_b2 = (const float*)d_in[9];
    const float* fcT_w1 = (const float*)d_in[10];
    const float* fcT_b1 = (const float*)d_in[11];
    const float* fcT_w2 = (const float*)d_in[12];
    const float* fcT_b2 = (const float*)d_in[13];
    const float* fcCT_w = (const float*)d_in[14];
    const float* fcCT_b = (const float*)d_in[15];
    float* out = (float*)d_out;

    float* ws = (float*)d_ws;
    size_t o_w    = 0;                                   // 300*896
    size_t o_r    = o_w  + 300 * 896;                    // 300*1024
    size_t o_ga   = o_r  + 300 * 1024;                   // 300*128
    size_t o_PT   = o_ga + 300 * 128;                    // TPAD*300 float4
    size_t o_NV   = o_PT + (size_t)TPAD * NSS * 4;       // TPAD*300*128 float2
    size_t o_pQ   = o_NV + (size_t)TPAD * NSS * 128 * 2;
    size_t o_pC   = o_pQ + (size_t)NROWS * 2;
    size_t o_w1bf = o_pC + (size_t)NROWS * 2;
    size_t o_w2bf = o_w1bf + 8192;

    float* wsite = ws + o_w;
    float* rsite = ws + o_r;
    float* gaw   = ws + o_ga;
    float4* PT   = (float4*)(ws + o_PT);
    float2* NV   = (float2*)(ws + o_NV);
    float* pQ    = ws + o_pQ;
    float* pC    = ws + o_pC;
    unsigned short* w1bf = (unsigned short*)(ws + o_w1bf);
    unsigned short* w2bf = (unsigned short*)(ws + o_w2bf);

    k_prep<<<448, 256, 0, stream>>>(fcT_w1, fcT_w2, w1bf, w2bf);
    k_site<<<dim3(30, 8), 256, 0, stream>>>(xc, fcW_w1, fcW_b1, fcW_w2, fcW_b2,
                                            fcR_w1, fcR_b1, fcR_w2, fcR_b2, wsite, rsite);
    k_softmax_ga<<<300, 128, 0, stream>>>(wsite, gaw);
    int nblk2 = (NROWS + 63) / 64;   // 1711
    k_fcT<<<nblk2, 512, 0, stream>>>(x, xc, w1bf, fcT_b1, w2bf, fcT_b2, PT, NV);
    k_scan<<<600, 64, 0, stream>>>(xc, wsite, rsite, gaw, fcCT_w, fcCT_b,
                                   PT, NV, pQ, pC);
    k_final<<<(NROWS + 255) / 256, 256, 0, stream>>>(pQ, pC, out);
}

// Round 5
// 161.480 us; speedup vs baseline: 6.2519x; 1.2497x over previous
//
#include <hip/hip_runtime.h>
#include <math.h>

#define NTT 365
#define NSS 300
#define NROWS (NTT*NSS)   // 109500
#define TPAD 384          // padded time steps for branchless prefetch

using bf16x8 = __attribute__((ext_vector_type(8))) short;
using f32x4  = __attribute__((ext_vector_type(4))) float;

__device__ __forceinline__ float sigf(float v) { return 1.0f / (1.0f + __expf(-v)); }

__device__ __forceinline__ float tanhfast(float x) {
    float e = __expf(2.0f * x);
    return 1.0f - 2.0f * __builtin_amdgcn_rcpf(1.0f + e);
}

__device__ __forceinline__ unsigned short f2bf(float f) {
    unsigned u = __builtin_bit_cast(unsigned, f);
    u += 0x7FFFu + ((u >> 16) & 1u);
    return (unsigned short)(u >> 16);
}

// ---------------- K0: swizzle fcT weights to fragment-major bf16 ----------------
// w1s: [tile(16)][ks(2)][lane(64)][8]  tile covers 16 out-cols, K padded 38->64
// w2s: [tile(24)][ks(8)][lane(64)][8]
__global__ __launch_bounds__(256) void k_prep(const float* __restrict__ w1,
                                              const float* __restrict__ w2,
                                              unsigned short* __restrict__ w1s,
                                              unsigned short* __restrict__ w2s)
{
    int G = blockIdx.x * 256 + threadIdx.x;
    if (G < 2048) {
        int lane = G & 63, ks = (G >> 6) & 1, tile = G >> 7;
        int o = tile * 16 + (lane & 15);
        int kb = ks * 32 + (lane >> 4) * 8;
        unsigned short tmp[8];
#pragma unroll
        for (int e = 0; e < 8; ++e) {
            int k = kb + e;
            tmp[e] = (k < 38) ? f2bf(w1[o * 38 + k]) : (unsigned short)0;
        }
        *(bf16x8*)(w1s + (size_t)G * 8) = *(bf16x8*)tmp;
    } else if (G < 2048 + 12288) {
        int G2 = G - 2048;
        int lane = G2 & 63, ks = (G2 >> 6) & 7, tile = G2 >> 9;
        int o = tile * 16 + (lane & 15);
        int kb = ks * 32 + (lane >> 4) * 8;
        unsigned short tmp[8];
#pragma unroll
        for (int e = 0; e < 8; ++e) tmp[e] = f2bf(w2[o * 256 + kb + e]);
        *(bf16x8*)(w2s + (size_t)G2 * 8) = *(bf16x8*)tmp;
    }
}

// ---------------- K1: per-site MLPs, output-sliced grid (30 x 8) ----------------
__global__ __launch_bounds__(256) void k_site(
    const float* __restrict__ xc,
    const float* __restrict__ wW1, const float* __restrict__ bW1,
    const float* __restrict__ wW2, const float* __restrict__ bW2,
    const float* __restrict__ wR1, const float* __restrict__ bR1,
    const float* __restrict__ wR2, const float* __restrict__ bR2,
    float* __restrict__ wsite, float* __restrict__ rsite)
{
    __shared__ float xcb[10][32];
    __shared__ float hW[10][256];
    __shared__ float hR[10][256];
    int tid = threadIdx.x;
    int s0 = blockIdx.x * 10;
    int os = blockIdx.y;              // 0..7 output slice
    for (int i = tid; i < 10 * 32; i += 256) xcb[i / 32][i % 32] = xc[s0 * 32 + i];
    __syncthreads();
    {
        int j = tid;
        float aW[10], aR[10];
#pragma unroll
        for (int r = 0; r < 10; ++r) { aW[r] = bW1[j]; aR[r] = bR1[j]; }
        for (int k = 0; k < 32; ++k) {
            float wv = wW1[j * 32 + k], rv = wR1[j * 32 + k];
#pragma unroll
            for (int r = 0; r < 10; ++r) { float xv = xcb[r][k]; aW[r] += xv * wv; aR[r] += xv * rv; }
        }
#pragma unroll
        for (int r = 0; r < 10; ++r) { hW[r][j] = tanhfast(aW[r]); hR[r][j] = tanhfast(aR[r]); }
    }
    __syncthreads();
    if (tid < 240) {
        int o_lin = os * 240 + tid;   // 0..1919
        float acc[10];
        if (o_lin < 896) {
            int o = o_lin;
#pragma unroll
            for (int r = 0; r < 10; ++r) acc[r] = bW2[o];
            for (int k = 0; k < 256; ++k) {
                float wv = wW2[o * 256 + k];
#pragma unroll
                for (int r = 0; r < 10; ++r) acc[r] += hW[r][k] * wv;
            }
#pragma unroll
            for (int r = 0; r < 10; ++r) wsite[(s0 + r) * 896 + o] = acc[r];
        } else {
            int o = o_lin - 896;      // 0..1023
#pragma unroll
            for (int r = 0; r < 10; ++r) acc[r] = bR2[o];
            for (int k = 0; k < 256; ++k) {
                float wv = wR2[o * 256 + k];
#pragma unroll
                for (int r = 0; r < 10; ++r) acc[r] += hR[r][k] * wv;
            }
#pragma unroll
            for (int r = 0; r < 10; ++r) rsite[(s0 + r) * 1024 + o] = acc[r];
        }
    }
}

// ---------------- K1b: softmax of ga over h per site ----------------
__global__ __launch_bounds__(128) void k_softmax_ga(const float* __restrict__ wsite,
                                                    float* __restrict__ ga)
{
    int s = blockIdx.x, tid = threadIdx.x;
    __shared__ float red[2];
    float v = wsite[s * 896 + 6 * 128 + tid];
    float m = v;
#pragma unroll
    for (int off = 32; off >= 1; off >>= 1) m = fmaxf(m, __shfl_xor(m, off));
    if ((tid & 63) == 0) red[tid >> 6] = m;
    __syncthreads();
    m = fmaxf(red[0], red[1]);
    __syncthreads();
    float e = __expf(v - m);
    float ssum = e;
#pragma unroll
    for (int off = 32; off >= 1; off >>= 1) ssum += __shfl_xor(ssum, off);
    if ((tid & 63) == 0) red[tid >> 6] = ssum;
    __syncthreads();
    ssum = red[0] + red[1];
    ga[s * 128 + tid] = e / ssum;
}

// ---------------- K2: fcT MLP via bf16 MFMA -> PT, NVu{bf16 net, bf16 vm} ----------------
__global__ __launch_bounds__(512) void k_fcT(
    const float* __restrict__ x, const float* __restrict__ xc,
    const unsigned short* __restrict__ w1s, const float* __restrict__ b1,
    const unsigned short* __restrict__ w2s, const float* __restrict__ b2,
    float4* __restrict__ PT, unsigned* __restrict__ NVu)
{
    __shared__ unsigned short A1[64][72];
    __shared__ unsigned short hb[64][264];
    __shared__ float2 pfE[64];           // {P*(1-vf), 2*E}
    int tid = threadIdx.x;
    int row0 = blockIdx.x * 64;

    for (int idx = tid; idx < 64 * 64; idx += 512) {
        int r = idx >> 6, c = idx & 63;
        int g = row0 + r;
        float val = 0.0f;
        if (g < NROWS) {
            if (c < 6) val = x[g * 6 + c];
            else if (c < 38) { int s = g % NSS; val = xc[s * 32 + (c - 6)]; }
        }
        A1[r][c] = f2bf(val);
    }
    if (tid < 64) {
        int r = tid, g = row0 + r;
        float P = 0, E = 0, T1 = 0, T2 = 0;
        if (g < NROWS) { P = x[g * 6]; E = x[g * 6 + 1]; T1 = x[g * 6 + 2]; T2 = x[g * 6 + 3]; }
        float den = T2 - T1;
        float dg = (den == 0.0f) ? 1.0f : den;
        float ratio = fminf(fmaxf((T1 + T2) / dg, -1.0f), 1.0f);
        float vf = acosf(ratio) * (1.0f / 3.1415f);
        vf = (T1 >= 0.0f) ? 0.0f : ((T2 <= 0.0f) ? 1.0f : vf);
        pfE[r] = make_float2(P * (1.0f - vf), 2.0f * E);
        if (g < NROWS) PT[g] = make_float4(P * vf, T1, T2, vf);
    }
    __syncthreads();

    int lane = tid & 63, wv = tid >> 6;
    int r16 = lane & 15;
    int kg = (lane >> 4) * 8;     // k offset within 32-chunk
    int rq = (lane >> 4) * 4;     // row offset of C frag

    // ---- layer 1: [64 x 64(Kpad)] @ [256 x 64]^T -> hidden (bf16) ----
    {
        int mt = wv & 3, nb = (wv >> 2) * 8;
        f32x4 acc[8];
#pragma unroll
        for (int i = 0; i < 8; ++i) acc[i] = (f32x4){0.f, 0.f, 0.f, 0.f};
#pragma unroll
        for (int ks = 0; ks < 2; ++ks) {
            bf16x8 a = *(const bf16x8*)&A1[mt * 16 + r16][ks * 32 + kg];
#pragma unroll
            for (int i = 0; i < 8; ++i) {
                bf16x8 b = *(const bf16x8*)(w1s + ((size_t)(((nb + i) * 2 + ks) * 64 + lane) << 3));
                acc[i] = __builtin_amdgcn_mfma_f32_16x16x32_bf16(a, b, acc[i], 0, 0, 0);
            }
        }
#pragma unroll
        for (int i = 0; i < 8; ++i) {
            int col = (nb + i) * 16 + r16;
            float bias = b1[col];
#pragma unroll
            for (int j = 0; j < 4; ++j) {
                int row = mt * 16 + rq + j;
                hb[row][col] = f2bf(tanhfast(acc[i][j] + bias));
            }
        }
    }
    __syncthreads();

    // ---- layer 2: [64 x 256] @ [384 x 256]^T, wave w -> col tiles {w, w+8, w+16} ----
    {
        int t0 = wv, t1 = wv + 8, t2 = wv + 16;
        f32x4 acc[4][3];
#pragma unroll
        for (int m = 0; m < 4; ++m)
#pragma unroll
            for (int c = 0; c < 3; ++c) acc[m][c] = (f32x4){0.f, 0.f, 0.f, 0.f};
#pragma unroll
        for (int ks = 0; ks < 8; ++ks) {
            bf16x8 b0 = *(const bf16x8*)(w2s + ((size_t)((t0 * 8 + ks) * 64 + lane) << 3));
            bf16x8 b1v = *(const bf16x8*)(w2s + ((size_t)((t1 * 8 + ks) * 64 + lane) << 3));
            bf16x8 b2v = *(const bf16x8*)(w2s + ((size_t)((t2 * 8 + ks) * 64 + lane) << 3));
#pragma unroll
            for (int m = 0; m < 4; ++m) {
                bf16x8 a = *(const bf16x8*)&hb[m * 16 + r16][ks * 32 + kg];
                acc[m][0] = __builtin_amdgcn_mfma_f32_16x16x32_bf16(a, b0, acc[m][0], 0, 0, 0);
                acc[m][1] = __builtin_amdgcn_mfma_f32_16x16x32_bf16(a, b1v, acc[m][1], 0, 0, 0);
                acc[m][2] = __builtin_amdgcn_mfma_f32_16x16x32_bf16(a, b2v, acc[m][2], 0, 0, 0);
            }
        }
        int hcol = wv * 16 + r16;     // h in [0,128)
        float bias0 = b2[hcol], bias1 = b2[128 + hcol], bias2 = b2[256 + hcol];
#pragma unroll
        for (int m = 0; m < 4; ++m) {
            float2 pf[4];
#pragma unroll
            for (int j = 0; j < 4; ++j) pf[j] = pfE[m * 16 + rq + j];
#pragma unroll
            for (int j = 0; j < 4; ++j) {
                int r = m * 16 + rq + j;
                int g = row0 + r;
                if (g < NROWS) {
                    float vi = fminf(fmaxf((acc[m][0][j] + bias0) * (1.0f / 3.0f) + 0.5f, 0.0f), 1.0f);
                    float pl = pf[j].x * vi;
                    float ev = pf[j].y * fmaxf(acc[m][1][j] + bias1, 0.0f);
                    float vmv = __expf(acc[m][2][j] + bias2);
                    unsigned pk = (unsigned)f2bf(pl - ev) | ((unsigned)f2bf(vmv) << 16);
                    NVu[(size_t)g * 128 + hcol] = pk;
                }
            }
        }
    }
}

// ---------------- K3: scan + fused conv; branchless 16-deep prefetch ----------------
__global__ __launch_bounds__(64) void k_scan(
    const float* __restrict__ xc,
    const float* __restrict__ wsite, const float* __restrict__ rsite,
    const float* __restrict__ gaw,
    const float* __restrict__ ctw, const float* __restrict__ ctb,
    const float4* __restrict__ PTg, const unsigned* __restrict__ NVu,
    float* __restrict__ pQ, float* __restrict__ pC)
{
    __shared__ float4 ptlds[TPAD];                 // 6144 B
    __shared__ __align__(16) float red[16][68];    // 4352 B; rows 0..7 q, 8..15 c
    int lane = threadIdx.x;
    int b = blockIdx.x;
    int s = b >> 1, half = b & 1;
    int h = half * 64 + lane;

    // one-time PT stage (single wave per block: no barrier needed)
    for (int t = lane; t < TPAD; t += 64) ptlds[t] = PTg[(size_t)t * NSS + s];

    const float* wrow = wsite + s * 896;
    float kp = sigf(wrow[0 * 128 + h]);
    float ks = sigf(wrow[1 * 128 + h]);
    float kg = sigf(wrow[2 * 128 + h]);
    float gp = sigf(wrow[3 * 128 + h]);
    float gpc = 1.0f - gp;
    float gL = __expf(wrow[4 * 128 + h]) * 2.0f;
    float kpgl = kp * gL;
    float qb = fmaxf(wrow[5 * 128 + h], 0.0f);
    float ga = gaw[s * 128 + h];
    float rt0 = fmaxf(rsite[s * 1024 + h * 8 + 0], 0.0f) * ga;
    float rt1 = fmaxf(rsite[s * 1024 + h * 8 + 1], 0.0f) * ga;
    float rt2 = fmaxf(rsite[s * 1024 + h * 8 + 2], 0.0f) * ga;
    float rt3 = fmaxf(rsite[s * 1024 + h * 8 + 3], 0.0f) * ga;
    float rt4 = fmaxf(rsite[s * 1024 + h * 8 + 4], 0.0f) * ga;
    float rt5 = fmaxf(rsite[s * 1024 + h * 8 + 5], 0.0f) * ga;
    float rt6 = fmaxf(rsite[s * 1024 + h * 8 + 6], 0.0f) * ga;
    float rt7 = fmaxf(rsite[s * 1024 + h * 8 + 7], 0.0f) * ga;
    const float L2E = 1.4426950408889634f;
    const float LG01 = -3.3219280948873623f;      // log2(0.1): folds the /10 into cp
    float cpw0, cpw1, cpb, csw0, csw1, csb, cgw0, cgw1, cgb;
    {
        const float* wr = ctw + (0 * 128 + h) * 34;
        float base = ctb[0 * 128 + h];
        for (int k = 0; k < 32; ++k) base += wr[2 + k] * xc[s * 32 + k];
        cpw0 = wr[0] * L2E; cpw1 = wr[1] * L2E; cpb = base * L2E + LG01;
    }
    {
        const float* wr = ctw + (1 * 128 + h) * 34;
        float base = ctb[1 * 128 + h];
        for (int k = 0; k < 32; ++k) base += wr[2 + k] * xc[s * 32 + k];
        csw0 = wr[0] * L2E; csw1 = wr[1] * L2E; csb = base * L2E;
    }
    {
        const float* wr = ctw + (2 * 128 + h) * 34;
        float base = ctb[2 * 128 + h];
        for (int k = 0; k < 32; ++k) base += wr[2 + k] * xc[s * 32 + k];
        cgw0 = wr[0] * L2E; cgw1 = wr[1] * L2E; cgb = base * L2E;
    }
    float Sf = 0.0f, Ss = 0.0f, Sg = 0.0f;
    float q0 = 0, q1 = 0, q2 = 0, q3 = 0, q4 = 0, q5 = 0, q6 = 0, q7 = 0;
    float c0 = 0, c1 = 0, c2 = 0, c3 = 0, c4 = 0, c5 = 0, c6 = 0, c7 = 0;

    // 16-deep NV register ring (branchless: arrays padded to TPAD steps)
    const unsigned* nvbase = NVu + (size_t)s * 128 + h;
    unsigned nv[16];
#pragma unroll
    for (int i = 0; i < 16; ++i) nv[i] = nvbase[(size_t)i * NSS * 128];

    // 4-deep PT pipeline from LDS
    float4 pt[4];
#pragma unroll
    for (int i = 0; i < 4; ++i) pt[i] = ptlds[i];

    auto reduce8 = [&](int base) {
        int v = lane >> 2, sub = lane & 3;
        const float4* rp = (const float4*)&red[v][0];
        float4 a0 = rp[sub * 4 + 0];
        float4 a1 = rp[sub * 4 + 1];
        float4 a2 = rp[sub * 4 + 2];
        float4 a3 = rp[sub * 4 + 3];
        float sA = (a0.x + a0.y) + (a0.z + a0.w);
        float sB = (a1.x + a1.y) + (a1.z + a1.w);
        float sC = (a2.x + a2.y) + (a2.z + a2.w);
        float sD = (a3.x + a3.y) + (a3.z + a3.w);
        float sm = (sA + sB) + (sC + sD);
        sm += __shfl_xor(sm, 1);
        sm += __shfl_xor(sm, 2);
        int t = base + (v & 7);
        if (sub == 0 && t < NTT) {
            float* bp = (v < 8) ? pQ : pC;
            bp[((size_t)t * NSS + s) * 2 + half] = sm;
        }
    };

    for (int tb = 0; tb < 368; tb += 16) {
#pragma unroll
        for (int u = 0; u < 16; ++u) {
            int t = tb + u;
            unsigned nvu = nv[u];
            float net = __builtin_bit_cast(float, nvu << 16);
            float vm  = __builtin_bit_cast(float, nvu & 0xFFFF0000u);
            // branchless prefetch, 16 ahead (padded arrays)
            nv[u] = nvbase[(size_t)(t + 16) * NSS * 128];
            float psv = pt[u & 3].x, T1 = pt[u & 3].y, T2 = pt[u & 3].z;
            pt[u & 3] = ptlds[t + 4];
            float t1v = Sf + psv;
            float qf = fminf(t1v, vm);
            Sf = fmaxf(t1v - vm, 0.0f);
            float H = fmaxf(Ss + qf + net, 0.0f);
            float qp = fmaxf(kp * H - kpgl, 0.0f);
            float qs = ks * fminf(H, gL);
            Ss = H - qp - qs;
            float qso = qs * gpc;
            float qsg = qs * gp;
            float tg = Sg + qsg;
            float qg = kg * tg + qb;
            Sg = tg - qg;
            float cp = exp2f(cpw0 * T1 + cpw1 * T2 + cpb);
            float cs = exp2f(csw0 * T1 + csw1 * T2 + csb);
            float cg = exp2f(cgw0 * T1 + cgw1 * T2 + cgb);
            float QS = qp + qso + qg;
            float CS = qp * cp + qso * cs + qg * cg;
            q0 += QS * rt0; q1 += QS * rt1; q2 += QS * rt2; q3 += QS * rt3;
            q4 += QS * rt4; q5 += QS * rt5; q6 += QS * rt6; q7 += QS * rt7;
            c0 += CS * rt0; c1 += CS * rt1; c2 += CS * rt2; c3 += CS * rt3;
            c4 += CS * rt4; c5 += CS * rt5; c6 += CS * rt6; c7 += CS * rt7;
            red[u & 7][lane] = q0;
            red[8 + (u & 7)][lane] = c0;
            q0 = q1; q1 = q2; q2 = q3; q3 = q4; q4 = q5; q5 = q6; q6 = q7; q7 = 0.0f;
            c0 = c1; c1 = c2; c2 = c3; c3 = c4; c4 = c5; c5 = c6; c6 = c7; c7 = 0.0f;
            if (u == 7) reduce8(tb);
            if (u == 15) reduce8(tb + 8);
        }
    }
}

// ---------------- K4: combine halves, divide ----------------
__global__ __launch_bounds__(256) void k_final(const float* __restrict__ pQ,
                                               const float* __restrict__ pC,
                                               float* __restrict__ out)
{
    int i = blockIdx.x * 256 + threadIdx.x;
    if (i < NROWS) {
        float q = pQ[i * 2] + pQ[i * 2 + 1];
        float c = pC[i * 2] + pC[i * 2 + 1];
        out[i] = q;
        out[NROWS + i] = c / q;
    }
}

extern "C" void kernel_launch(void* const* d_in, const int* in_sizes, int n_in,
                              void* d_out, int out_size, void* d_ws, size_t ws_size,
                              hipStream_t stream)
{
    const float* x      = (const float*)d_in[0];
    const float* xc     = (const float*)d_in[1];
    const float* fcR_w1 = (const float*)d_in[2];
    const float* fcR_b1 = (const float*)d_in[3];
    const float* fcR_w2 = (const float*)d_in[4];
    const float* fcR_b2 = (const float*)d_in[5];
    const float* fcW_w1 = (const float*)d_in[6];
    const float* fcW_b1 = (const float*)d_in[7];
    const float* fcW_w2 = (const float*)d_in[8];
    const float* fcW_b2 = (const float*)d_in[9];
    const float* fcT_w1 = (const float*)d_in[10];
    const float* fcT_b1 = (const float*)d_in[11];
    const float* fcT_w2 = (const float*)d_in[12];
    const float* fcT_b2 = (const float*)d_in[13];
    const float* fcCT_w = (const float*)d_in[14];
    const float* fcCT_b = (const float*)d_in[15];
    float* out = (float*)d_out;

    float* ws = (float*)d_ws;
    size_t o_w    = 0;                                   // 300*896
    size_t o_r    = o_w  + 300 * 896;                    // 300*1024
    size_t o_ga   = o_r  + 300 * 1024;                   // 300*128
    size_t o_PT   = o_ga + 300 * 128;                    // TPAD*300 float4
    size_t o_NV   = o_PT + (size_t)TPAD * NSS * 4;       // TPAD*300*128 u32
    size_t o_pQ   = o_NV + (size_t)TPAD * NSS * 128;
    size_t o_pC   = o_pQ + (size_t)NROWS * 2;
    size_t o_w1bf = o_pC + (size_t)NROWS * 2;
    size_t o_w2bf = o_w1bf + 8192;

    float* wsite = ws + o_w;
    float* rsite = ws + o_r;
    float* gaw   = ws + o_ga;
    float4* PT   = (float4*)(ws + o_PT);
    unsigned* NVu = (unsigned*)(ws + o_NV);
    float* pQ    = ws + o_pQ;
    float* pC    = ws + o_pC;
    unsigned short* w1s = (unsigned short*)(ws + o_w1bf);
    unsigned short* w2s = (unsigned short*)(ws + o_w2bf);

    k_prep<<<56, 256, 0, stream>>>(fcT_w1, fcT_w2, w1s, w2s);
    k_site<<<dim3(30, 8), 256, 0, stream>>>(xc, fcW_w1, fcW_b1, fcW_w2, fcW_b2,
                                            fcR_w1, fcR_b1, fcR_w2, fcR_b2, wsite, rsite);
    k_softmax_ga<<<300, 128, 0, stream>>>(wsite, gaw);
    int nblk2 = (NROWS + 63) / 64;   // 1711
    k_fcT<<<nblk2, 512, 0, stream>>>(x, xc, w1s, fcT_b1, w2s, fcT_b2, PT, NVu);
    k_scan<<<600, 64, 0, stream>>>(xc, wsite, rsite, gaw, fcCT_w, fcCT_b,
                                   PT, NVu, pQ, pC);
    k_final<<<(NROWS + 255) / 256, 256, 0, stream>>>(pQ, pC, out);
}